// Round 1
// baseline (512.669 us; speedup 1.0000x reference)
//
#include <hip/hip_runtime.h>
#include <stdint.h>

#define BB 2
#define HH 16
#define NN 2048
#define DD 128
#define EE 2048

typedef short s16x8 __attribute__((ext_vector_type(8)));
typedef float fx4 __attribute__((ext_vector_type(4)));

static __device__ __forceinline__ unsigned short f2bf(float f) {
  unsigned u = __builtin_bit_cast(unsigned, f);
  u += 0x7fffu + ((u >> 16) & 1u);
  return (unsigned short)(u >> 16);
}
static __device__ __forceinline__ float bf2f(unsigned short h) {
  unsigned u = ((unsigned)h) << 16;
  return __builtin_bit_cast(float, u);
}
static __device__ __forceinline__ void gload_lds16(const void* g, void* l) {
  __builtin_amdgcn_global_load_lds(
      (const __attribute__((address_space(1))) unsigned int*)g,
      (__attribute__((address_space(3))) unsigned int*)l, 16, 0, 0);
}

// ---------------- fp32 -> bf16 convert (vectorized) ----------------
__global__ __launch_bounds__(256) void f2b_kernel(const float* __restrict__ in,
                                                  unsigned short* __restrict__ out,
                                                  int n4) {
  int i = blockIdx.x * 256 + threadIdx.x;
  if (i < n4) {
    float4 v = ((const float4*)in)[i];
    uint2 o;
    o.x = ((unsigned)f2bf(v.y) << 16) | f2bf(v.x);
    o.y = ((unsigned)f2bf(v.w) << 16) | f2bf(v.z);
    ((uint2*)out)[i] = o;
  }
}

// ---------------- NT GEMM: C[m,n] = sum_k A[m,k]*B[n,k] (bf16 in, fp32 acc) --
// m97 structure: 128x128 tile, BK=32, 4 waves (2x2, each 64x64), 16x16x32 MFMA
#define GBM 128
#define GBN 128
#define GBK 32

__global__ __launch_bounds__(256) void gemm_bt(const unsigned short* __restrict__ A,
                                               const unsigned short* __restrict__ B,
                                               unsigned short* __restrict__ Cb,
                                               float* __restrict__ Cf,
                                               int M, int N, int K) {
  __shared__ alignas(16) unsigned short Alds[GBM * GBK];
  __shared__ alignas(16) unsigned short Blds[GBN * GBK];
  const int tid = threadIdx.x;
  const int wave = tid >> 6, lane = tid & 63;
  const int g = lane >> 4, lr = lane & 15;
  const int mtiles = M / GBM;
  const int mt = blockIdx.x % mtiles, nt = blockIdx.x / mtiles;
  const int m0 = mt * GBM, n0 = nt * GBN;
  const int wr = wave >> 1, wc = wave & 1;

  fx4 acc[4][4];
#pragma unroll
  for (int i = 0; i < 4; ++i)
#pragma unroll
    for (int j = 0; j < 4; ++j) acc[i][j] = (fx4){0.f, 0.f, 0.f, 0.f};

  // staging: wave w covers rows [w*32, +32) of each tile; 2 loads of 16 rows
  const int srow = wave * 32 + (lane >> 2);
  const int scolb = (lane & 3) * 16;  // byte within 64B row
  const unsigned char* Ag = (const unsigned char*)(A + (size_t)(m0 + srow) * K) + scolb;
  const unsigned char* Bg = (const unsigned char*)(B + (size_t)(n0 + srow) * K) + scolb;
  unsigned short* Al = Alds + wave * 32 * GBK;
  unsigned short* Bl = Blds + wave * 32 * GBK;
  const size_t rowb = (size_t)K * 2;

  for (int k0 = 0; k0 < K; k0 += GBK) {
    const unsigned char* ag = Ag + (size_t)k0 * 2;
    const unsigned char* bg = Bg + (size_t)k0 * 2;
    gload_lds16(ag, Al);
    gload_lds16(ag + 16 * rowb, Al + 16 * GBK);
    gload_lds16(bg, Bl);
    gload_lds16(bg + 16 * rowb, Bl + 16 * GBK);
    __syncthreads();
    s16x8 af[4], bf[4];
#pragma unroll
    for (int i = 0; i < 4; ++i)
      af[i] = *(const s16x8*)(Alds + (wr * 64 + i * 16 + lr) * GBK + 8 * g);
#pragma unroll
    for (int i = 0; i < 4; ++i)
      bf[i] = *(const s16x8*)(Blds + (wc * 64 + i * 16 + lr) * GBK + 8 * g);
#pragma unroll
    for (int i = 0; i < 4; ++i)
#pragma unroll
      for (int j = 0; j < 4; ++j)
        acc[i][j] = __builtin_amdgcn_mfma_f32_16x16x32_bf16(af[i], bf[j], acc[i][j], 0, 0, 0);
    __syncthreads();
  }
  // epilogue: D row = 4*g + r, col = lr  (m89/m91-verified mapping)
#pragma unroll
  for (int i = 0; i < 4; ++i) {
    int row = m0 + wr * 64 + i * 16 + 4 * g;
#pragma unroll
    for (int j = 0; j < 4; ++j) {
      int col = n0 + wc * 64 + j * 16 + lr;
#pragma unroll
      for (int r = 0; r < 4; ++r) {
        float v = acc[i][j][r];
        if (Cf) Cf[(size_t)(row + r) * N + col] = v;
        else    Cb[(size_t)(row + r) * N + col] = f2bf(v);
      }
    }
  }
}

// ---------------- kvh projection: out[m, j] = dot(x[m,:], Wkvh[j,:]) ---------
__global__ __launch_bounds__(256) void kvh_gemm(const unsigned short* __restrict__ X,
                                                const float* __restrict__ W,
                                                float* __restrict__ out) {
  int t = threadIdx.x;
  int m = blockIdx.x * 8 + (t >> 5);
  int j = t & 31;
  const unsigned short* xr = X + (size_t)m * EE;
  const float* wr = W + (size_t)j * EE;
  float s = 0.f;
  for (int k = 0; k < EE; k += 8) {
    s16x8 xv = *(const s16x8*)(xr + k);
#pragma unroll
    for (int u = 0; u < 8; ++u) s += bf2f((unsigned short)xv[u]) * wr[k + u];
  }
  out[(size_t)m * 32 + j] = s;
}

// ---------------- RoPE on q (with (b,n,h,d) -> (b,h,n,d) transpose) ----------
__global__ __launch_bounds__(256) void rope_q(const unsigned short* __restrict__ qp,
                                              unsigned short* __restrict__ qo) {
  int idx = blockIdx.x * 256 + threadIdx.x;  // B*H*N*64
  int i = idx & 63;
  int n = (idx >> 6) & (NN - 1);
  int bh = idx >> 17;
  int b = bh >> 4, h = bh & 15;
  unsigned v = *(const unsigned*)(qp + ((size_t)(b * NN + n) * EE + h * DD + 2 * i));
  float x1 = bf2f((unsigned short)(v & 0xffff));
  float x2 = bf2f((unsigned short)(v >> 16));
  float inv = __expf(-0.14391156831212787f * (float)i);  // 10000^(-i/64)
  float ang = (float)n * inv;
  float sn, cs;
  __sincosf(ang, &sn, &cs);
  float o1 = x1 * cs - x2 * sn, o2 = x1 * sn + x2 * cs;
  unsigned ov = ((unsigned)f2bf(o2) << 16) | f2bf(o1);
  *(unsigned*)(qo + ((size_t)bh * NN + n) * DD + 2 * i) = ov;
}

// ---------------- RoPE on shared k (kv rows stride 256, cols 0..127) ---------
__global__ __launch_bounds__(256) void rope_k(const unsigned short* __restrict__ kv,
                                              unsigned short* __restrict__ ko) {
  int idx = blockIdx.x * 256 + threadIdx.x;  // B*N*64
  int i = idx & 63;
  int bn = idx >> 6;
  int n = bn & (NN - 1);
  unsigned v = *(const unsigned*)(kv + (size_t)bn * 256 + 2 * i);
  float x1 = bf2f((unsigned short)(v & 0xffff));
  float x2 = bf2f((unsigned short)(v >> 16));
  float inv = __expf(-0.14391156831212787f * (float)i);
  float ang = (float)n * inv;
  float sn, cs;
  __sincosf(ang, &sn, &cs);
  float o1 = x1 * cs - x2 * sn, o2 = x1 * sn + x2 * cs;
  unsigned ov = ((unsigned)f2bf(o2) << 16) | f2bf(o1);
  *(unsigned*)(ko + (size_t)bn * DD + 2 * i) = ov;
}

// ---------------- causal flash attention -------------------------------------
// grid (qt=32, h=16, b=2), block 256 (4 waves x 16 q-rows). KBLK=64.
// khead folded into scores; vhead folded into P. K/V are the SHARED (per-b) ones.
#define QB 64
#define KB 64

__global__ __launch_bounds__(256) void attn(const unsigned short* __restrict__ Q,
                                            const unsigned short* __restrict__ Kr,
                                            const unsigned short* __restrict__ Vr,
                                            const float* __restrict__ KVH,
                                            unsigned short* __restrict__ O) {
  __shared__ alignas(16) unsigned char Klds[64 * 256];   // [key][d] bf16, chunk^=(key&7)
  __shared__ alignas(16) unsigned char Vlds[128 * 128];  // [d][key] bf16, chunk^=(d&7)
  __shared__ alignas(16) unsigned char Plds[4 * 16 * 128]; // per-wave [q][key], chunk^=(q&7)

  const int qt = blockIdx.x;
  const int h = blockIdx.y;
  const int b = blockIdx.z;
  const int tid = threadIdx.x;
  const int wave = tid >> 6, lane = tid & 63;
  const int g = lane >> 4, lr = lane & 15;
  const size_t bh = (size_t)(b * HH + h);
  const int qbase = qt * QB + wave * 16;

  // Q fragments in regs: A-operand row = lr, k = dc*32 + 8g
  s16x8 qf[4];
  {
    const unsigned short* qp = Q + (bh * NN + qbase + lr) * DD + 8 * g;
#pragma unroll
    for (int dc = 0; dc < 4; ++dc) qf[dc] = *(const s16x8*)(qp + dc * 32);
  }

  float m_run[4], l_run[4];
  fx4 oacc[8];
#pragma unroll
  for (int r = 0; r < 4; ++r) { m_run[r] = -1e30f; l_run[r] = 0.f; }
#pragma unroll
  for (int d = 0; d < 8; ++d) oacc[d] = (fx4){0.f, 0.f, 0.f, 0.f};

  const float scale = 0.08838834764831845f;  // 1/sqrt(128)
  const unsigned short* Kb = Kr + (size_t)b * NN * DD;
  const unsigned short* Vb = Vr + (size_t)b * NN * 256;  // rows stride 256
  const int vkp = tid & 31, vdg = tid >> 5;
  const int nkt = qt + 1;

  for (int kt = 0; kt < nkt; ++kt) {
    const int key0 = kt * KB;
    __syncthreads();  // previous tile's reads complete before overwrite
    // --- stage K via global_load_lds, source pre-swizzled (m173 pattern) ---
#pragma unroll
    for (int j = 0; j < 4; ++j) {
      int rl = wave * 16 + j * 4 + (lane >> 4);
      int ch = (lane & 15) ^ (rl & 7);
      const unsigned char* gp = (const unsigned char*)(Kb + (size_t)(key0 + rl) * DD) + ch * 16;
      gload_lds16(gp, (void*)(Klds + (wave * 16 + j * 4) * 256));
    }
    // --- stage V^T (reg-staged, swizzled): keys 2vkp,2vkp+1 x d[vdg*16,+16) ---
    {
      const unsigned short* v0 = Vb + (size_t)(key0 + 2 * vkp) * 256 + vdg * 16;
      s16x8 a0 = *(const s16x8*)(v0);
      s16x8 a1 = *(const s16x8*)(v0 + 8);
      s16x8 b0 = *(const s16x8*)(v0 + 256);
      s16x8 b1 = *(const s16x8*)(v0 + 264);
#pragma unroll
      for (int u = 0; u < 16; ++u) {
        int d = vdg * 16 + u;
        unsigned short e0 = (unsigned short)((u < 8) ? a0[u] : a1[u - 8]);
        unsigned short e1 = (unsigned short)((u < 8) ? b0[u] : b1[u - 8]);
        unsigned w32 = ((unsigned)e1 << 16) | e0;
        int chunk = (vkp >> 2) ^ (d & 7);
        *(unsigned*)(Vlds + d * 128 + chunk * 16 + (vkp & 3) * 4) = w32;
      }
    }
    __syncthreads();

    // --- QK^T ---
    fx4 sacc[4];
#pragma unroll
    for (int kb = 0; kb < 4; ++kb) {
      sacc[kb] = (fx4){0.f, 0.f, 0.f, 0.f};
#pragma unroll
      for (int dc = 0; dc < 4; ++dc) {
        int key = kb * 16 + lr;
        int chunk = (dc * 4 + g) ^ (key & 7);
        s16x8 kf = *(const s16x8*)(Klds + key * 256 + chunk * 16);
        sacc[kb] = __builtin_amdgcn_mfma_f32_16x16x32_bf16(qf[dc], kf, sacc[kb], 0, 0, 0);
      }
    }
    // --- scale by khead, causal mask, online softmax ---
    float khv[4], vhv[4];
#pragma unroll
    for (int kb = 0; kb < 4; ++kb) {
      int keyg = key0 + kb * 16 + lr;
      khv[kb] = KVH[((size_t)b * NN + keyg) * 32 + h];
      vhv[kb] = KVH[((size_t)b * NN + keyg) * 32 + 16 + h];
    }
    float tmax[4];
#pragma unroll
    for (int r = 0; r < 4; ++r) tmax[r] = -1e30f;
    const bool diag = (kt == qt);
#pragma unroll
    for (int kb = 0; kb < 4; ++kb) {
      int keyg = key0 + kb * 16 + lr;
#pragma unroll
      for (int r = 0; r < 4; ++r) {
        int qg = qbase + 4 * g + r;
        float s = sacc[kb][r] * scale * khv[kb];
        if (diag && keyg > qg) s = -1e30f;
        sacc[kb][r] = s;
        tmax[r] = fmaxf(tmax[r], s);
      }
    }
#pragma unroll
    for (int r = 0; r < 4; ++r) {
      float v = tmax[r];
      v = fmaxf(v, __shfl_xor(v, 1));
      v = fmaxf(v, __shfl_xor(v, 2));
      v = fmaxf(v, __shfl_xor(v, 4));
      v = fmaxf(v, __shfl_xor(v, 8));
      tmax[r] = v;
    }
    float corr[4];
#pragma unroll
    for (int r = 0; r < 4; ++r) {
      float mnew = fmaxf(m_run[r], tmax[r]);
      corr[r] = __expf(m_run[r] - mnew);
      m_run[r] = mnew;
    }
    float rsum[4] = {0.f, 0.f, 0.f, 0.f};
#pragma unroll
    for (int kb = 0; kb < 4; ++kb) {
#pragma unroll
      for (int r = 0; r < 4; ++r) {
        float p = __expf(sacc[kb][r] - m_run[r]);
        rsum[r] += p;
        int ql = 4 * g + r;
        int keyl = kb * 16 + lr;
        int chunk = (keyl >> 3) ^ (ql & 7);
        *(unsigned short*)(Plds + wave * 2048 + ql * 128 + chunk * 16 + (keyl & 7) * 2) =
            f2bf(p * vhv[kb]);  // fold vhead into P
      }
    }
#pragma unroll
    for (int r = 0; r < 4; ++r) {
      float v = rsum[r];
      v += __shfl_xor(v, 1);
      v += __shfl_xor(v, 2);
      v += __shfl_xor(v, 4);
      v += __shfl_xor(v, 8);
      l_run[r] = l_run[r] * corr[r] + v;
    }
#pragma unroll
    for (int d = 0; d < 8; ++d)
#pragma unroll
      for (int r = 0; r < 4; ++r) oacc[d][r] *= corr[r];

    // --- PV ---
    s16x8 pa[2];
#pragma unroll
    for (int kk = 0; kk < 2; ++kk) {
      int chunk = (kk * 4 + g) ^ (lr & 7);
      pa[kk] = *(const s16x8*)(Plds + wave * 2048 + lr * 128 + chunk * 16);
    }
#pragma unroll
    for (int dc = 0; dc < 8; ++dc) {
#pragma unroll
      for (int kk = 0; kk < 2; ++kk) {
        int d = dc * 16 + lr;
        int chunk = (kk * 4 + g) ^ (d & 7);
        s16x8 vf = *(const s16x8*)(Vlds + d * 128 + chunk * 16);
        oacc[dc] = __builtin_amdgcn_mfma_f32_16x16x32_bf16(pa[kk], vf, oacc[dc], 0, 0, 0);
      }
    }
  }
  // --- epilogue: O[b, n, h, d] bf16 ---
#pragma unroll
  for (int r = 0; r < 4; ++r) {
    int qg = qbase + 4 * g + r;
    float inv = 1.0f / l_run[r];
    unsigned short* orow = O + (((size_t)b * NN + qg) * HH + h) * DD;
#pragma unroll
    for (int dc = 0; dc < 8; ++dc) orow[dc * 16 + lr] = f2bf(oacc[dc][r] * inv);
  }
}

// ---------------- launch -----------------------------------------------------
extern "C" void kernel_launch(void* const* d_in, const int* in_sizes, int n_in,
                              void* d_out, int out_size, void* d_ws, size_t ws_size,
                              hipStream_t stream) {
  const float* x = (const float*)d_in[0];
  const float* Wq = (const float*)d_in[1];
  const float* Wkv = (const float*)d_in[2];
  const float* Wkvh = (const float*)d_in[3];
  const float* Wo = (const float*)d_in[4];
  float* out = (float*)d_out;
  char* ws = (char*)d_ws;

  unsigned short* xb    = (unsigned short*)(ws + 0);          // 16 MB (b*n, E) bf16
  unsigned short* obuf  = xb;                                  // alias: x dead by attn
  unsigned short* wqb   = (unsigned short*)(ws + 16777216);    // 8 MB
  unsigned short* wkvb  = (unsigned short*)(ws + 25165824);    // 1 MB
  unsigned short* wob   = (unsigned short*)(ws + 26214400);    // 8 MB
  unsigned short* qproj = (unsigned short*)(ws + 34603008);    // 16 MB (b*n, h*d)
  unsigned short* kvb   = (unsigned short*)(ws + 51380224);    // 2 MB (b*n, 256)
  float*          kvhb  = (float*)(ws + 53477376);             // 0.5 MB (b*n, 32)
  unsigned short* qrope = (unsigned short*)(ws + 54001664);    // 16 MB (b*h, n, d)
  unsigned short* krope = (unsigned short*)(ws + 70778880);    // 1 MB (b*n, d)

  f2b_kernel<<<8192, 256, 0, stream>>>(x, xb, 2097152);
  f2b_kernel<<<4096, 256, 0, stream>>>(Wq, wqb, 1048576);
  f2b_kernel<<<512, 256, 0, stream>>>(Wkv, wkvb, 131072);
  f2b_kernel<<<4096, 256, 0, stream>>>(Wo, wob, 1048576);

  gemm_bt<<<512, 256, 0, stream>>>(xb, wqb, qproj, (float*)nullptr, 4096, 2048, 2048);
  gemm_bt<<<64, 256, 0, stream>>>(xb, wkvb, kvb, (float*)nullptr, 4096, 256, 2048);
  kvh_gemm<<<512, 256, 0, stream>>>(xb, Wkvh, kvhb);

  rope_q<<<16384, 256, 0, stream>>>(qproj, qrope);
  rope_k<<<1024, 256, 0, stream>>>(kvb, krope);

  dim3 ag(NN / QB, HH, BB);
  attn<<<ag, 256, 0, stream>>>(qrope, krope, kvb + 128, kvhb, obuf);

  gemm_bt<<<512, 256, 0, stream>>>(obuf, wob, (unsigned short*)nullptr, out, 4096, 2048, 2048);
}

// Round 2
// 431.757 us; speedup vs baseline: 1.1874x; 1.1874x over previous
//
#include <hip/hip_runtime.h>
#include <stdint.h>

#define BB 2
#define HH 16
#define NN 2048
#define DD 128
#define EE 2048

typedef short s16x8 __attribute__((ext_vector_type(8)));
typedef float fx4 __attribute__((ext_vector_type(4)));

static __device__ __forceinline__ unsigned short f2bf(float f) {
  unsigned u = __builtin_bit_cast(unsigned, f);
  u += 0x7fffu + ((u >> 16) & 1u);
  return (unsigned short)(u >> 16);
}
static __device__ __forceinline__ float bf2f(unsigned short h) {
  unsigned u = ((unsigned)h) << 16;
  return __builtin_bit_cast(float, u);
}
static __device__ __forceinline__ void gload_lds16(const void* g, void* l) {
  __builtin_amdgcn_global_load_lds(
      (const __attribute__((address_space(1))) unsigned int*)g,
      (__attribute__((address_space(3))) unsigned int*)l, 16, 0, 0);
}

// ---------------- fp32 -> bf16 convert (vectorized) ----------------
__global__ __launch_bounds__(256) void f2b_kernel(const float* __restrict__ in,
                                                  unsigned short* __restrict__ out,
                                                  int n4) {
  int i = blockIdx.x * 256 + threadIdx.x;
  if (i < n4) {
    float4 v = ((const float4*)in)[i];
    uint2 o;
    o.x = ((unsigned)f2bf(v.y) << 16) | f2bf(v.x);
    o.y = ((unsigned)f2bf(v.w) << 16) | f2bf(v.z);
    ((uint2*)out)[i] = o;
  }
}

// ---------------- NT GEMM: C[m,n] = sum_k A[m,k]*B[n,k] (bf16 in, fp32 acc) --
#define GBM 128
#define GBN 128
#define GBK 32

__global__ __launch_bounds__(256) void gemm_bt(const unsigned short* __restrict__ A,
                                               const unsigned short* __restrict__ B,
                                               unsigned short* __restrict__ Cb,
                                               float* __restrict__ Cf,
                                               int M, int N, int K) {
  __shared__ alignas(16) unsigned short Alds[GBM * GBK];
  __shared__ alignas(16) unsigned short Blds[GBN * GBK];
  const int tid = threadIdx.x;
  const int wave = tid >> 6, lane = tid & 63;
  const int g = lane >> 4, lr = lane & 15;
  const int mtiles = M / GBM;
  const int mt = blockIdx.x % mtiles, nt = blockIdx.x / mtiles;
  const int m0 = mt * GBM, n0 = nt * GBN;
  const int wr = wave >> 1, wc = wave & 1;

  fx4 acc[4][4];
#pragma unroll
  for (int i = 0; i < 4; ++i)
#pragma unroll
    for (int j = 0; j < 4; ++j) acc[i][j] = (fx4){0.f, 0.f, 0.f, 0.f};

  const int srow = wave * 32 + (lane >> 2);
  const int scolb = (lane & 3) * 16;
  const unsigned char* Ag = (const unsigned char*)(A + (size_t)(m0 + srow) * K) + scolb;
  const unsigned char* Bg = (const unsigned char*)(B + (size_t)(n0 + srow) * K) + scolb;
  unsigned short* Al = Alds + wave * 32 * GBK;
  unsigned short* Bl = Blds + wave * 32 * GBK;
  const size_t rowb = (size_t)K * 2;

  for (int k0 = 0; k0 < K; k0 += GBK) {
    const unsigned char* ag = Ag + (size_t)k0 * 2;
    const unsigned char* bg = Bg + (size_t)k0 * 2;
    gload_lds16(ag, Al);
    gload_lds16(ag + 16 * rowb, Al + 16 * GBK);
    gload_lds16(bg, Bl);
    gload_lds16(bg + 16 * rowb, Bl + 16 * GBK);
    __syncthreads();
    s16x8 af[4], bf[4];
#pragma unroll
    for (int i = 0; i < 4; ++i)
      af[i] = *(const s16x8*)(Alds + (wr * 64 + i * 16 + lr) * GBK + 8 * g);
#pragma unroll
    for (int i = 0; i < 4; ++i)
      bf[i] = *(const s16x8*)(Blds + (wc * 64 + i * 16 + lr) * GBK + 8 * g);
#pragma unroll
    for (int i = 0; i < 4; ++i)
#pragma unroll
      for (int j = 0; j < 4; ++j)
        acc[i][j] = __builtin_amdgcn_mfma_f32_16x16x32_bf16(af[i], bf[j], acc[i][j], 0, 0, 0);
    __syncthreads();
  }
#pragma unroll
  for (int i = 0; i < 4; ++i) {
    int row = m0 + wr * 64 + i * 16 + 4 * g;
#pragma unroll
    for (int j = 0; j < 4; ++j) {
      int col = n0 + wc * 64 + j * 16 + lr;
#pragma unroll
      for (int r = 0; r < 4; ++r) {
        float v = acc[i][j][r];
        if (Cf) Cf[(size_t)(row + r) * N + col] = v;
        else    Cb[(size_t)(row + r) * N + col] = f2bf(v);
      }
    }
  }
}

// ---------------- kvh projection -> transposed packed [b][h][n]{k,v} --------
__global__ __launch_bounds__(256) void kvh_gemm(const unsigned short* __restrict__ X,
                                                const float* __restrict__ W,
                                                float* __restrict__ out) {
  int t = threadIdx.x;
  int m = blockIdx.x * 8 + (t >> 5);
  int j = t & 31;
  const unsigned short* xr = X + (size_t)m * EE;
  const float* wr = W + (size_t)j * EE;
  float s = 0.f;
  for (int k = 0; k < EE; k += 8) {
    s16x8 xv = *(const s16x8*)(xr + k);
#pragma unroll
    for (int u = 0; u < 8; ++u) s += bf2f((unsigned short)xv[u]) * wr[k + u];
  }
  int b = m >> 11, n = m & (NN - 1);
  // packed float2 planes: [b][h][n][{k_head,v_head}]
  out[(((size_t)(b * HH + (j & 15))) * NN + n) * 2 + (j >> 4)] = s;
}

// ---------------- RoPE on q ((b,n,h,d) -> (b,h,n,d)) ------------------------
__global__ __launch_bounds__(256) void rope_q(const unsigned short* __restrict__ qp,
                                              unsigned short* __restrict__ qo) {
  int idx = blockIdx.x * 256 + threadIdx.x;
  int i = idx & 63;
  int n = (idx >> 6) & (NN - 1);
  int bh = idx >> 17;
  int b = bh >> 4, h = bh & 15;
  unsigned v = *(const unsigned*)(qp + ((size_t)(b * NN + n) * EE + h * DD + 2 * i));
  float x1 = bf2f((unsigned short)(v & 0xffff));
  float x2 = bf2f((unsigned short)(v >> 16));
  float inv = __expf(-0.14391156831212787f * (float)i);
  float ang = (float)n * inv;
  float sn, cs;
  __sincosf(ang, &sn, &cs);
  float o1 = x1 * cs - x2 * sn, o2 = x1 * sn + x2 * cs;
  unsigned ov = ((unsigned)f2bf(o2) << 16) | f2bf(o1);
  *(unsigned*)(qo + ((size_t)bh * NN + n) * DD + 2 * i) = ov;
}

// ---------------- RoPE on shared k ------------------------------------------
__global__ __launch_bounds__(256) void rope_k(const unsigned short* __restrict__ kv,
                                              unsigned short* __restrict__ ko) {
  int idx = blockIdx.x * 256 + threadIdx.x;
  int i = idx & 63;
  int bn = idx >> 6;
  int n = bn & (NN - 1);
  unsigned v = *(const unsigned*)(kv + (size_t)bn * 256 + 2 * i);
  float x1 = bf2f((unsigned short)(v & 0xffff));
  float x2 = bf2f((unsigned short)(v >> 16));
  float inv = __expf(-0.14391156831212787f * (float)i);
  float ang = (float)n * inv;
  float sn, cs;
  __sincosf(ang, &sn, &cs);
  float o1 = x1 * cs - x2 * sn, o2 = x1 * sn + x2 * cs;
  unsigned ov = ((unsigned)f2bf(o2) << 16) | f2bf(o1);
  *(unsigned*)(ko + (size_t)bn * DD + 2 * i) = ov;
}

// ---------------- causal flash attention, load-balanced ----------------------
// grid (16 qpairs, 16 h, 2 b); block = 4 waves x 16 q-rows; KBLK=64.
// Each block handles q-tiles qp and 31-qp -> exactly 33 K-tiles per block.
#define QB 64
#define KB 64

__global__ __launch_bounds__(256) void attn(const unsigned short* __restrict__ Q,
                                            const unsigned short* __restrict__ Kr,
                                            const unsigned short* __restrict__ Vr,
                                            const float* __restrict__ KVHP,
                                            unsigned short* __restrict__ O) {
  __shared__ alignas(16) unsigned char Klds[64 * 256];
  __shared__ alignas(16) unsigned char Vlds[128 * 128];
  __shared__ alignas(16) unsigned char Plds[4 * 16 * 128];

  const int qp = blockIdx.x;
  const int h = blockIdx.y;
  const int b = blockIdx.z;
  const int tid = threadIdx.x;
  const int wave = tid >> 6, lane = tid & 63;
  const int g = lane >> 4, lr = lane & 15;
  const size_t bh = (size_t)(b * HH + h);

  const float scale = 0.08838834764831845f;  // 1/sqrt(128)
  const unsigned short* Kb = Kr + (size_t)b * NN * DD;
  const unsigned short* Vb = Vr + (size_t)b * NN * 256;
  const float2* KVp = (const float2*)KVHP + (size_t)(b * HH + h) * NN;
  const int vkp = tid & 31, vdg = tid >> 5;

  for (int half = 0; half < 2; ++half) {
    const int qt = half ? (31 - qp) : qp;
    const int qbase = qt * QB + wave * 16;

    s16x8 qf[4];
    {
      const unsigned short* qptr = Q + (bh * NN + qbase + lr) * DD + 8 * g;
#pragma unroll
      for (int dc = 0; dc < 4; ++dc) qf[dc] = *(const s16x8*)(qptr + dc * 32);
    }

    float m_run[4], l_run[4];
    fx4 oacc[8];
#pragma unroll
    for (int r = 0; r < 4; ++r) { m_run[r] = -1e30f; l_run[r] = 0.f; }
#pragma unroll
    for (int d = 0; d < 8; ++d) oacc[d] = (fx4){0.f, 0.f, 0.f, 0.f};

    const int nkt = qt + 1;
    for (int kt = 0; kt < nkt; ++kt) {
      const int key0 = kt * KB;
      __syncthreads();
      // --- stage K (global_load_lds, pre-swizzled source) ---
#pragma unroll
      for (int j = 0; j < 4; ++j) {
        int rl = wave * 16 + j * 4 + (lane >> 4);
        int ch = (lane & 15) ^ (rl & 7);
        const unsigned char* gp = (const unsigned char*)(Kb + (size_t)(key0 + rl) * DD) + ch * 16;
        gload_lds16(gp, (void*)(Klds + (wave * 16 + j * 4) * 256));
      }
      // --- stage V^T (reg-staged, swizzled) ---
      {
        const unsigned short* v0 = Vb + (size_t)(key0 + 2 * vkp) * 256 + vdg * 16;
        s16x8 a0 = *(const s16x8*)(v0);
        s16x8 a1 = *(const s16x8*)(v0 + 8);
        s16x8 b0 = *(const s16x8*)(v0 + 256);
        s16x8 b1 = *(const s16x8*)(v0 + 264);
#pragma unroll
        for (int u = 0; u < 16; ++u) {
          int d = vdg * 16 + u;
          unsigned short e0 = (unsigned short)((u < 8) ? a0[u] : a1[u - 8]);
          unsigned short e1 = (unsigned short)((u < 8) ? b0[u] : b1[u - 8]);
          unsigned w32 = ((unsigned)e1 << 16) | e0;
          int chunk = (vkp >> 2) ^ (d & 7);
          *(unsigned*)(Vlds + d * 128 + chunk * 16 + (vkp & 3) * 4) = w32;
        }
      }
      __syncthreads();

      // --- QK^T ---
      fx4 sacc[4];
#pragma unroll
      for (int kb = 0; kb < 4; ++kb) {
        sacc[kb] = (fx4){0.f, 0.f, 0.f, 0.f};
#pragma unroll
        for (int dc = 0; dc < 4; ++dc) {
          int key = kb * 16 + lr;
          int chunk = (dc * 4 + g) ^ (key & 7);
          s16x8 kf = *(const s16x8*)(Klds + key * 256 + chunk * 16);
          sacc[kb] = __builtin_amdgcn_mfma_f32_16x16x32_bf16(qf[dc], kf, sacc[kb], 0, 0, 0);
        }
      }
      // --- head scales (coalesced packed loads), mask, online softmax ---
      float khs[4], vhv[4];
#pragma unroll
      for (int kb = 0; kb < 4; ++kb) {
        float2 kv2 = KVp[key0 + kb * 16 + lr];
        khs[kb] = kv2.x * scale;
        vhv[kb] = kv2.y;
      }
      float tmax[4];
#pragma unroll
      for (int r = 0; r < 4; ++r) tmax[r] = -1e30f;
      const bool diag = (kt == qt);
#pragma unroll
      for (int kb = 0; kb < 4; ++kb) {
        int keyg = key0 + kb * 16 + lr;
#pragma unroll
        for (int r = 0; r < 4; ++r) {
          int qg = qbase + 4 * g + r;
          float s = sacc[kb][r] * khs[kb];
          if (diag && keyg > qg) s = -1e30f;
          sacc[kb][r] = s;
          tmax[r] = fmaxf(tmax[r], s);
        }
      }
#pragma unroll
      for (int r = 0; r < 4; ++r) {
        float v = tmax[r];
        v = fmaxf(v, __shfl_xor(v, 1));
        v = fmaxf(v, __shfl_xor(v, 2));
        v = fmaxf(v, __shfl_xor(v, 4));
        v = fmaxf(v, __shfl_xor(v, 8));
        tmax[r] = v;
      }
      // --- T13 defer-rescale: skip O-rescale when max growth <= 8 ---
      float dm = -1e30f;
#pragma unroll
      for (int r = 0; r < 4; ++r) dm = fmaxf(dm, tmax[r] - m_run[r]);
      if (!__all(dm <= 8.0f)) {
        float corr[4];
#pragma unroll
        for (int r = 0; r < 4; ++r) {
          float mnew = fmaxf(m_run[r], tmax[r]);
          corr[r] = __expf(m_run[r] - mnew);
          m_run[r] = mnew;
          l_run[r] *= corr[r];
        }
#pragma unroll
        for (int d = 0; d < 8; ++d)
#pragma unroll
          for (int r = 0; r < 4; ++r) oacc[d][r] *= corr[r];
      }
      float rsum[4] = {0.f, 0.f, 0.f, 0.f};
#pragma unroll
      for (int kb = 0; kb < 4; ++kb) {
#pragma unroll
        for (int r = 0; r < 4; ++r) {
          float p = __expf(sacc[kb][r] - m_run[r]);
          rsum[r] += p;
          int ql = 4 * g + r;
          int keyl = kb * 16 + lr;
          int chunk = (keyl >> 3) ^ (ql & 7);
          *(unsigned short*)(Plds + wave * 2048 + ql * 128 + chunk * 16 + (keyl & 7) * 2) =
              f2bf(p * vhv[kb]);
        }
      }
#pragma unroll
      for (int r = 0; r < 4; ++r) {
        float v = rsum[r];
        v += __shfl_xor(v, 1);
        v += __shfl_xor(v, 2);
        v += __shfl_xor(v, 4);
        v += __shfl_xor(v, 8);
        l_run[r] += v;
      }

      // --- PV ---
      s16x8 pa[2];
#pragma unroll
      for (int kk = 0; kk < 2; ++kk) {
        int chunk = (kk * 4 + g) ^ (lr & 7);
        pa[kk] = *(const s16x8*)(Plds + wave * 2048 + lr * 128 + chunk * 16);
      }
#pragma unroll
      for (int dc = 0; dc < 8; ++dc) {
#pragma unroll
        for (int kk = 0; kk < 2; ++kk) {
          int d = dc * 16 + lr;
          int chunk = (kk * 4 + g) ^ (d & 7);
          s16x8 vf = *(const s16x8*)(Vlds + d * 128 + chunk * 16);
          oacc[dc] = __builtin_amdgcn_mfma_f32_16x16x32_bf16(pa[kk], vf, oacc[dc], 0, 0, 0);
        }
      }
    }
    // --- epilogue for this half ---
#pragma unroll
    for (int r = 0; r < 4; ++r) {
      int qg = qbase + 4 * g + r;
      float inv = 1.0f / l_run[r];
      unsigned short* orow = O + (((size_t)b * NN + qg) * HH + h) * DD;
#pragma unroll
      for (int dc = 0; dc < 8; ++dc) orow[dc * 16 + lr] = f2bf(oacc[dc][r] * inv);
    }
  }
}

// ---------------- launch -----------------------------------------------------
extern "C" void kernel_launch(void* const* d_in, const int* in_sizes, int n_in,
                              void* d_out, int out_size, void* d_ws, size_t ws_size,
                              hipStream_t stream) {
  const float* x = (const float*)d_in[0];
  const float* Wq = (const float*)d_in[1];
  const float* Wkv = (const float*)d_in[2];
  const float* Wkvh = (const float*)d_in[3];
  const float* Wo = (const float*)d_in[4];
  float* out = (float*)d_out;
  char* ws = (char*)d_ws;

  unsigned short* xb    = (unsigned short*)(ws + 0);          // 16 MB
  unsigned short* obuf  = xb;                                  // alias: x dead by attn
  unsigned short* wqb   = (unsigned short*)(ws + 16777216);    // 8 MB
  unsigned short* wkvb  = (unsigned short*)(ws + 25165824);    // 1 MB
  unsigned short* wob   = (unsigned short*)(ws + 26214400);    // 8 MB
  unsigned short* qproj = (unsigned short*)(ws + 34603008);    // 16 MB
  unsigned short* kvb   = (unsigned short*)(ws + 51380224);    // 2 MB
  float*          kvhb  = (float*)(ws + 53477376);             // 0.5 MB packed [b][h][n]{k,v}
  unsigned short* qrope = (unsigned short*)(ws + 54001664);    // 16 MB
  unsigned short* krope = (unsigned short*)(ws + 70778880);    // 1 MB

  f2b_kernel<<<8192, 256, 0, stream>>>(x, xb, 2097152);
  f2b_kernel<<<4096, 256, 0, stream>>>(Wq, wqb, 1048576);
  f2b_kernel<<<512, 256, 0, stream>>>(Wkv, wkvb, 131072);
  f2b_kernel<<<4096, 256, 0, stream>>>(Wo, wob, 1048576);

  gemm_bt<<<512, 256, 0, stream>>>(xb, wqb, qproj, (float*)nullptr, 4096, 2048, 2048);
  gemm_bt<<<64, 256, 0, stream>>>(xb, wkvb, kvb, (float*)nullptr, 4096, 256, 2048);
  kvh_gemm<<<512, 256, 0, stream>>>(xb, Wkvh, kvhb);

  rope_q<<<16384, 256, 0, stream>>>(qproj, qrope);
  rope_k<<<1024, 256, 0, stream>>>(kvb, krope);

  dim3 ag(16, HH, BB);
  attn<<<ag, 256, 0, stream>>>(qrope, krope, kvb + 128, kvhb, obuf);

  gemm_bt<<<512, 256, 0, stream>>>(obuf, wob, (unsigned short*)nullptr, out, 4096, 2048, 2048);
}

// Round 3
// 411.213 us; speedup vs baseline: 1.2467x; 1.0500x over previous
//
#include <hip/hip_runtime.h>
#include <stdint.h>

#define BB 2
#define HH 16
#define NN 2048
#define DD 128
#define EE 2048

typedef short s16x8 __attribute__((ext_vector_type(8)));
typedef float fx4 __attribute__((ext_vector_type(4)));

static __device__ __forceinline__ unsigned short f2bf(float f) {
  unsigned u = __builtin_bit_cast(unsigned, f);
  u += 0x7fffu + ((u >> 16) & 1u);
  return (unsigned short)(u >> 16);
}
static __device__ __forceinline__ float bf2f(unsigned short h) {
  unsigned u = ((unsigned)h) << 16;
  return __builtin_bit_cast(float, u);
}
static __device__ __forceinline__ void gload_lds16(const void* g, void* l) {
  __builtin_amdgcn_global_load_lds(
      (const __attribute__((address_space(1))) unsigned int*)g,
      (__attribute__((address_space(3))) unsigned int*)l, 16, 0, 0);
}

// ---------------- fp32 -> bf16 convert (vectorized) ----------------
__global__ __launch_bounds__(256) void f2b_kernel(const float* __restrict__ in,
                                                  unsigned short* __restrict__ out,
                                                  int n4) {
  int i = blockIdx.x * 256 + threadIdx.x;
  if (i < n4) {
    float4 v = ((const float4*)in)[i];
    uint2 o;
    o.x = ((unsigned)f2bf(v.y) << 16) | f2bf(v.x);
    o.y = ((unsigned)f2bf(v.w) << 16) | f2bf(v.z);
    ((uint2*)out)[i] = o;
  }
}

// ---------------- NT GEMM: C[m,n] = sum_k A[m,k]*B[n,k] (bf16 in, fp32 acc) --
#define GBM 128
#define GBN 128
#define GBK 32

__global__ __launch_bounds__(256) void gemm_bt(const unsigned short* __restrict__ A,
                                               const unsigned short* __restrict__ B,
                                               unsigned short* __restrict__ Cb,
                                               float* __restrict__ Cf,
                                               int M, int N, int K) {
  __shared__ alignas(16) unsigned short Alds[GBM * GBK];
  __shared__ alignas(16) unsigned short Blds[GBN * GBK];
  const int tid = threadIdx.x;
  const int wave = tid >> 6, lane = tid & 63;
  const int g = lane >> 4, lr = lane & 15;
  const int mtiles = M / GBM;
  const int mt = blockIdx.x % mtiles, nt = blockIdx.x / mtiles;
  const int m0 = mt * GBM, n0 = nt * GBN;
  const int wr = wave >> 1, wc = wave & 1;

  fx4 acc[4][4];
#pragma unroll
  for (int i = 0; i < 4; ++i)
#pragma unroll
    for (int j = 0; j < 4; ++j) acc[i][j] = (fx4){0.f, 0.f, 0.f, 0.f};

  const int srow = wave * 32 + (lane >> 2);
  const int scolb = (lane & 3) * 16;
  const unsigned char* Ag = (const unsigned char*)(A + (size_t)(m0 + srow) * K) + scolb;
  const unsigned char* Bg = (const unsigned char*)(B + (size_t)(n0 + srow) * K) + scolb;
  unsigned short* Al = Alds + wave * 32 * GBK;
  unsigned short* Bl = Blds + wave * 32 * GBK;
  const size_t rowb = (size_t)K * 2;

  for (int k0 = 0; k0 < K; k0 += GBK) {
    const unsigned char* ag = Ag + (size_t)k0 * 2;
    const unsigned char* bg = Bg + (size_t)k0 * 2;
    gload_lds16(ag, Al);
    gload_lds16(ag + 16 * rowb, Al + 16 * GBK);
    gload_lds16(bg, Bl);
    gload_lds16(bg + 16 * rowb, Bl + 16 * GBK);
    __syncthreads();
    s16x8 af[4], bf[4];
#pragma unroll
    for (int i = 0; i < 4; ++i)
      af[i] = *(const s16x8*)(Alds + (wr * 64 + i * 16 + lr) * GBK + 8 * g);
#pragma unroll
    for (int i = 0; i < 4; ++i)
      bf[i] = *(const s16x8*)(Blds + (wc * 64 + i * 16 + lr) * GBK + 8 * g);
#pragma unroll
    for (int i = 0; i < 4; ++i)
#pragma unroll
      for (int j = 0; j < 4; ++j)
        acc[i][j] = __builtin_amdgcn_mfma_f32_16x16x32_bf16(af[i], bf[j], acc[i][j], 0, 0, 0);
    __syncthreads();
  }
#pragma unroll
  for (int i = 0; i < 4; ++i) {
    int row = m0 + wr * 64 + i * 16 + 4 * g;
#pragma unroll
    for (int j = 0; j < 4; ++j) {
      int col = n0 + wc * 64 + j * 16 + lr;
#pragma unroll
      for (int r = 0; r < 4; ++r) {
        float v = acc[i][j][r];
        if (Cf) Cf[(size_t)(row + r) * N + col] = v;
        else    Cb[(size_t)(row + r) * N + col] = f2bf(v);
      }
    }
  }
}

// ---------------- kvh projection -> transposed packed [b][h][n]{k,v} --------
__global__ __launch_bounds__(256) void kvh_gemm(const unsigned short* __restrict__ X,
                                                const float* __restrict__ W,
                                                float* __restrict__ out) {
  int t = threadIdx.x;
  int m = blockIdx.x * 8 + (t >> 5);
  int j = t & 31;
  const unsigned short* xr = X + (size_t)m * EE;
  const float* wr = W + (size_t)j * EE;
  float s = 0.f;
  for (int k = 0; k < EE; k += 8) {
    s16x8 xv = *(const s16x8*)(xr + k);
#pragma unroll
    for (int u = 0; u < 8; ++u) s += bf2f((unsigned short)xv[u]) * wr[k + u];
  }
  int b = m >> 11, n = m & (NN - 1);
  out[(((size_t)(b * HH + (j & 15))) * NN + n) * 2 + (j >> 4)] = s;
}

// ---------------- RoPE on q ((b,n,h,d) -> (b,h,n,d)) ------------------------
__global__ __launch_bounds__(256) void rope_q(const unsigned short* __restrict__ qp,
                                              unsigned short* __restrict__ qo) {
  int idx = blockIdx.x * 256 + threadIdx.x;
  int i = idx & 63;
  int n = (idx >> 6) & (NN - 1);
  int bh = idx >> 17;
  int b = bh >> 4, h = bh & 15;
  unsigned v = *(const unsigned*)(qp + ((size_t)(b * NN + n) * EE + h * DD + 2 * i));
  float x1 = bf2f((unsigned short)(v & 0xffff));
  float x2 = bf2f((unsigned short)(v >> 16));
  float inv = __expf(-0.14391156831212787f * (float)i);
  float ang = (float)n * inv;
  float sn, cs;
  __sincosf(ang, &sn, &cs);
  float o1 = x1 * cs - x2 * sn, o2 = x1 * sn + x2 * cs;
  unsigned ov = ((unsigned)f2bf(o2) << 16) | f2bf(o1);
  *(unsigned*)(qo + ((size_t)bh * NN + n) * DD + 2 * i) = ov;
}

// ---------------- RoPE on shared k ------------------------------------------
__global__ __launch_bounds__(256) void rope_k(const unsigned short* __restrict__ kv,
                                              unsigned short* __restrict__ ko) {
  int idx = blockIdx.x * 256 + threadIdx.x;
  int i = idx & 63;
  int bn = idx >> 6;
  int n = bn & (NN - 1);
  unsigned v = *(const unsigned*)(kv + (size_t)bn * 256 + 2 * i);
  float x1 = bf2f((unsigned short)(v & 0xffff));
  float x2 = bf2f((unsigned short)(v >> 16));
  float inv = __expf(-0.14391156831212787f * (float)i);
  float ang = (float)n * inv;
  float sn, cs;
  __sincosf(ang, &sn, &cs);
  float o1 = x1 * cs - x2 * sn, o2 = x1 * sn + x2 * cs;
  unsigned ov = ((unsigned)f2bf(o2) << 16) | f2bf(o1);
  *(unsigned*)(ko + (size_t)bn * DD + 2 * i) = ov;
}

// ---------------- V transpose: kv[b*n][256] cols 128..255 -> vT[b][d][n] -----
__global__ __launch_bounds__(256) void vtrans(const unsigned short* __restrict__ kv,
                                              unsigned short* __restrict__ vT) {
  __shared__ unsigned short t[64][40];  // 64 n x 32 d, padded
  int bx = blockIdx.x;                  // 2*4*32 = 256 blocks
  int b = bx >> 7;
  int d0 = ((bx >> 5) & 3) * 32;
  int n0 = (bx & 31) * 64;
  int tid = threadIdx.x;
  {
    int i = tid >> 2;
    int c = (tid & 3) * 8;
    s16x8 v = *(const s16x8*)(kv + ((size_t)(b * NN + n0 + i)) * 256 + 128 + d0 + c);
#pragma unroll
    for (int u = 0; u < 8; ++u) t[i][c + u] = (unsigned short)v[u];
  }
  __syncthreads();
  {
    int j = tid >> 3;
    int cc = (tid & 7) * 8;
    s16x8 o;
#pragma unroll
    for (int u = 0; u < 8; ++u) o[u] = (short)t[cc + u][j];
    *(s16x8*)(vT + ((size_t)(b * DD + d0 + j)) * NN + n0 + cc) = o;
  }
}

// ---------------- causal flash attention, load-balanced ----------------------
// grid (16 qpairs, 16 h, 2 b); block = 4 waves x 16 q-rows; KBLK=64.
// q-tiles (qp, 31-qp) per block -> 33 K-tiles each. Softmax in log2 domain.
#define QB 64
#define KB 64

__global__ __launch_bounds__(256) void attn(const unsigned short* __restrict__ Q,
                                            const unsigned short* __restrict__ Kr,
                                            const unsigned short* __restrict__ VT,
                                            const float* __restrict__ KVHP,
                                            unsigned short* __restrict__ O) {
  __shared__ alignas(16) unsigned char Klds[64 * 256];    // [key][d], chunk^=(key&7)
  __shared__ alignas(16) unsigned char Vlds[128 * 128];   // [d][key], chunk^=(d&7)
  __shared__ alignas(16) unsigned char Plds[4 * 16 * 128];

  const int qp = blockIdx.x;
  const int h = blockIdx.y;
  const int b = blockIdx.z;
  const int tid = threadIdx.x;
  const int wave = tid >> 6, lane = tid & 63;
  const int g = lane >> 4, lr = lane & 15;
  const size_t bh = (size_t)(b * HH + h);

  // khead scale folded with 1/sqrt(d) and log2(e) (exp2-domain softmax)
  const float scale2 = 0.08838834764831845f * 1.4426950408889634f;
  const unsigned short* Kb = Kr + (size_t)b * NN * DD;
  const unsigned short* VTb = VT + (size_t)b * DD * NN;
  const float2* KVp = (const float2*)KVHP + (size_t)(b * HH + h) * NN;

  for (int half = 0; half < 2; ++half) {
    const int qt = half ? (31 - qp) : qp;
    const int qbase = qt * QB + wave * 16;

    s16x8 qf[4];
    {
      const unsigned short* qptr = Q + (bh * NN + qbase + lr) * DD + 8 * g;
#pragma unroll
      for (int dc = 0; dc < 4; ++dc) qf[dc] = *(const s16x8*)(qptr + dc * 32);
    }

    float m_run[4], l_run[4];
    fx4 oacc[8];
#pragma unroll
    for (int r = 0; r < 4; ++r) { m_run[r] = -1e30f; l_run[r] = 0.f; }
#pragma unroll
    for (int d = 0; d < 8; ++d) oacc[d] = (fx4){0.f, 0.f, 0.f, 0.f};

    const int nkt = qt + 1;
    for (int kt = 0; kt < nkt; ++kt) {
      const int key0 = kt * KB;
      __syncthreads();
      // --- stage K (global_load_lds, pre-swizzled source) ---
#pragma unroll
      for (int j = 0; j < 4; ++j) {
        int rl = wave * 16 + j * 4 + (lane >> 4);
        int ch = (lane & 15) ^ (rl & 7);
        const unsigned char* gp = (const unsigned char*)(Kb + (size_t)(key0 + rl) * DD) + ch * 16;
        gload_lds16(gp, (void*)(Klds + (wave * 16 + j * 4) * 256));
      }
      // --- stage V^T (global_load_lds from pre-transposed vT, swizzled src) ---
#pragma unroll
      for (int j = 0; j < 4; ++j) {
        int row = wave * 32 + j * 8 + (lane >> 3);
        int c = lane & 7;
        const unsigned short* gp = VTb + (size_t)row * NN + key0 + ((c ^ (row & 7)) * 8);
        gload_lds16(gp, (void*)(Vlds + (wave * 32 + j * 8) * 128));
      }
      // head scales (issue早 for latency overlap)
      float khs[4], vhv[4];
#pragma unroll
      for (int kb = 0; kb < 4; ++kb) {
        float2 kv2 = KVp[key0 + kb * 16 + lr];
        khs[kb] = kv2.x * scale2;
        vhv[kb] = kv2.y;
      }
      __syncthreads();

      // --- QK^T ---
      fx4 sacc[4];
#pragma unroll
      for (int kb = 0; kb < 4; ++kb) {
        sacc[kb] = (fx4){0.f, 0.f, 0.f, 0.f};
#pragma unroll
        for (int dc = 0; dc < 4; ++dc) {
          int key = kb * 16 + lr;
          int chunk = (dc * 4 + g) ^ (key & 7);
          s16x8 kf = *(const s16x8*)(Klds + key * 256 + chunk * 16);
          sacc[kb] = __builtin_amdgcn_mfma_f32_16x16x32_bf16(qf[dc], kf, sacc[kb], 0, 0, 0);
        }
      }
      // --- scale, mask (diag only), tile max ---
      float tmax[4];
#pragma unroll
      for (int r = 0; r < 4; ++r) tmax[r] = -1e30f;
      if (kt == qt) {
#pragma unroll
        for (int kb = 0; kb < 4; ++kb) {
          int keyg = key0 + kb * 16 + lr;
#pragma unroll
          for (int r = 0; r < 4; ++r) {
            int qg = qbase + 4 * g + r;
            float s = sacc[kb][r] * khs[kb];
            if (keyg > qg) s = -1e30f;
            sacc[kb][r] = s;
            tmax[r] = fmaxf(tmax[r], s);
          }
        }
      } else {
#pragma unroll
        for (int kb = 0; kb < 4; ++kb) {
#pragma unroll
          for (int r = 0; r < 4; ++r) {
            float s = sacc[kb][r] * khs[kb];
            sacc[kb][r] = s;
            tmax[r] = fmaxf(tmax[r], s);
          }
        }
      }
#pragma unroll
      for (int r = 0; r < 4; ++r) {
        float v = tmax[r];
        v = fmaxf(v, __shfl_xor(v, 1));
        v = fmaxf(v, __shfl_xor(v, 2));
        v = fmaxf(v, __shfl_xor(v, 4));
        v = fmaxf(v, __shfl_xor(v, 8));
        tmax[r] = v;
      }
      // --- T13 defer-rescale (log2 domain, bound 2^8) ---
      float dm = -1e30f;
#pragma unroll
      for (int r = 0; r < 4; ++r) dm = fmaxf(dm, tmax[r] - m_run[r]);
      if (!__all(dm <= 8.0f)) {
        float corr[4];
#pragma unroll
        for (int r = 0; r < 4; ++r) {
          float mnew = fmaxf(m_run[r], tmax[r]);
          corr[r] = exp2f(m_run[r] - mnew);
          m_run[r] = mnew;
          l_run[r] *= corr[r];
        }
#pragma unroll
        for (int d = 0; d < 8; ++d)
#pragma unroll
          for (int r = 0; r < 4; ++r) oacc[d][r] *= corr[r];
      }
      float rsum[4] = {0.f, 0.f, 0.f, 0.f};
#pragma unroll
      for (int kb = 0; kb < 4; ++kb) {
#pragma unroll
        for (int r = 0; r < 4; ++r) {
          float p = exp2f(sacc[kb][r] - m_run[r]);
          rsum[r] += p;
          int ql = 4 * g + r;
          int keyl = kb * 16 + lr;
          int chunk = (keyl >> 3) ^ (ql & 7);
          *(unsigned short*)(Plds + wave * 2048 + ql * 128 + chunk * 16 + (keyl & 7) * 2) =
              f2bf(p * vhv[kb]);
        }
      }
#pragma unroll
      for (int r = 0; r < 4; ++r) {
        float v = rsum[r];
        v += __shfl_xor(v, 1);
        v += __shfl_xor(v, 2);
        v += __shfl_xor(v, 4);
        v += __shfl_xor(v, 8);
        l_run[r] += v;
      }

      // --- PV ---
      s16x8 pa[2];
#pragma unroll
      for (int kk = 0; kk < 2; ++kk) {
        int chunk = (kk * 4 + g) ^ (lr & 7);
        pa[kk] = *(const s16x8*)(Plds + wave * 2048 + lr * 128 + chunk * 16);
      }
#pragma unroll
      for (int dc = 0; dc < 8; ++dc) {
#pragma unroll
        for (int kk = 0; kk < 2; ++kk) {
          int d = dc * 16 + lr;
          int chunk = (kk * 4 + g) ^ (d & 7);
          s16x8 vf = *(const s16x8*)(Vlds + d * 128 + chunk * 16);
          oacc[dc] = __builtin_amdgcn_mfma_f32_16x16x32_bf16(pa[kk], vf, oacc[dc], 0, 0, 0);
        }
      }
    }
    // --- epilogue for this half ---
#pragma unroll
    for (int r = 0; r < 4; ++r) {
      int qg = qbase + 4 * g + r;
      float inv = 1.0f / l_run[r];
      unsigned short* orow = O + (((size_t)b * NN + qg) * HH + h) * DD;
#pragma unroll
      for (int dc = 0; dc < 8; ++dc) orow[dc * 16 + lr] = f2bf(oacc[dc][r] * inv);
    }
  }
}

// ---------------- launch -----------------------------------------------------
extern "C" void kernel_launch(void* const* d_in, const int* in_sizes, int n_in,
                              void* d_out, int out_size, void* d_ws, size_t ws_size,
                              hipStream_t stream) {
  const float* x = (const float*)d_in[0];
  const float* Wq = (const float*)d_in[1];
  const float* Wkv = (const float*)d_in[2];
  const float* Wkvh = (const float*)d_in[3];
  const float* Wo = (const float*)d_in[4];
  float* out = (float*)d_out;
  char* ws = (char*)d_ws;

  unsigned short* xb    = (unsigned short*)(ws + 0);          // 16 MB
  unsigned short* obuf  = xb;                                  // alias: x dead by attn
  unsigned short* wqb   = (unsigned short*)(ws + 16777216);    // 8 MB
  unsigned short* vtb   = wqb;                                 // alias: wqb dead after q-GEMM
  unsigned short* wkvb  = (unsigned short*)(ws + 25165824);    // 1 MB
  unsigned short* wob   = (unsigned short*)(ws + 26214400);    // 8 MB
  unsigned short* qproj = (unsigned short*)(ws + 34603008);    // 16 MB
  unsigned short* kvb   = (unsigned short*)(ws + 51380224);    // 2 MB
  float*          kvhb  = (float*)(ws + 53477376);             // 0.5 MB packed [b][h][n]{k,v}
  unsigned short* qrope = (unsigned short*)(ws + 54001664);    // 16 MB
  unsigned short* krope = (unsigned short*)(ws + 70778880);    // 1 MB

  f2b_kernel<<<8192, 256, 0, stream>>>(x, xb, 2097152);
  f2b_kernel<<<4096, 256, 0, stream>>>(Wq, wqb, 1048576);
  f2b_kernel<<<512, 256, 0, stream>>>(Wkv, wkvb, 131072);
  f2b_kernel<<<4096, 256, 0, stream>>>(Wo, wob, 1048576);

  gemm_bt<<<512, 256, 0, stream>>>(xb, wqb, qproj, (float*)nullptr, 4096, 2048, 2048);
  gemm_bt<<<64, 256, 0, stream>>>(xb, wkvb, kvb, (float*)nullptr, 4096, 256, 2048);
  kvh_gemm<<<512, 256, 0, stream>>>(xb, Wkvh, kvhb);

  rope_q<<<16384, 256, 0, stream>>>(qproj, qrope);
  rope_k<<<1024, 256, 0, stream>>>(kvb, krope);
  vtrans<<<256, 256, 0, stream>>>(kvb, vtb);  // vT[b][d][n], reuses wqb space

  dim3 ag(16, HH, BB);
  attn<<<ag, 256, 0, stream>>>(qrope, krope, vtb, kvhb, obuf);

  gemm_bt<<<512, 256, 0, stream>>>(obuf, wob, (unsigned short*)nullptr, out, 4096, 2048, 2048);
}

// Round 4
// 274.139 us; speedup vs baseline: 1.8701x; 1.5000x over previous
//
#include <hip/hip_runtime.h>
#include <stdint.h>

#define BB 2
#define HH 16
#define NN 2048
#define DD 128
#define EE 2048
#define NQKV 2304  // 2048 q cols + 256 kv cols

typedef short s16x8 __attribute__((ext_vector_type(8)));
typedef float fx4 __attribute__((ext_vector_type(4)));

static __device__ __forceinline__ unsigned short f2bf(float f) {
  unsigned u = __builtin_bit_cast(unsigned, f);
  u += 0x7fffu + ((u >> 16) & 1u);
  return (unsigned short)(u >> 16);
}
static __device__ __forceinline__ float bf2f(unsigned short h) {
  unsigned u = ((unsigned)h) << 16;
  return __builtin_bit_cast(float, u);
}
static __device__ __forceinline__ void gload_lds16(const void* g, void* l) {
  __builtin_amdgcn_global_load_lds(
      (const __attribute__((address_space(1))) unsigned int*)g,
      (__attribute__((address_space(3))) unsigned int*)l, 16, 0, 0);
}

// ---------------- fp32 -> bf16 convert (vectorized) ----------------
__global__ __launch_bounds__(256) void f2b_kernel(const float* __restrict__ in,
                                                  unsigned short* __restrict__ out,
                                                  int n4) {
  int i = blockIdx.x * 256 + threadIdx.x;
  if (i < n4) {
    float4 v = ((const float4*)in)[i];
    uint2 o;
    o.x = ((unsigned)f2bf(v.y) << 16) | f2bf(v.x);
    o.y = ((unsigned)f2bf(v.w) << 16) | f2bf(v.z);
    ((uint2*)out)[i] = o;
  }
}

// ---------------- NT GEMM: C[m,n] = sum_k A[m,k]*B[n,k] (bf16 in, fp32 acc) --
#define GBM 128
#define GBN 128
#define GBK 32

__global__ __launch_bounds__(256) void gemm_bt(const unsigned short* __restrict__ A,
                                               const unsigned short* __restrict__ B,
                                               unsigned short* __restrict__ Cb,
                                               float* __restrict__ Cf,
                                               int M, int N, int K) {
  __shared__ alignas(16) unsigned short Alds[GBM * GBK];
  __shared__ alignas(16) unsigned short Blds[GBN * GBK];
  const int tid = threadIdx.x;
  const int wave = tid >> 6, lane = tid & 63;
  const int g = lane >> 4, lr = lane & 15;
  const int mtiles = M / GBM;
  const int mt = blockIdx.x % mtiles, nt = blockIdx.x / mtiles;
  const int m0 = mt * GBM, n0 = nt * GBN;
  const int wr = wave >> 1, wc = wave & 1;

  fx4 acc[4][4];
#pragma unroll
  for (int i = 0; i < 4; ++i)
#pragma unroll
    for (int j = 0; j < 4; ++j) acc[i][j] = (fx4){0.f, 0.f, 0.f, 0.f};

  const int srow = wave * 32 + (lane >> 2);
  const int scolb = (lane & 3) * 16;
  const unsigned char* Ag = (const unsigned char*)(A + (size_t)(m0 + srow) * K) + scolb;
  const unsigned char* Bg = (const unsigned char*)(B + (size_t)(n0 + srow) * K) + scolb;
  unsigned short* Al = Alds + wave * 32 * GBK;
  unsigned short* Bl = Blds + wave * 32 * GBK;
  const size_t rowb = (size_t)K * 2;

  for (int k0 = 0; k0 < K; k0 += GBK) {
    const unsigned char* ag = Ag + (size_t)k0 * 2;
    const unsigned char* bg = Bg + (size_t)k0 * 2;
    gload_lds16(ag, Al);
    gload_lds16(ag + 16 * rowb, Al + 16 * GBK);
    gload_lds16(bg, Bl);
    gload_lds16(bg + 16 * rowb, Bl + 16 * GBK);
    __syncthreads();
    s16x8 af[4], bf[4];
#pragma unroll
    for (int i = 0; i < 4; ++i)
      af[i] = *(const s16x8*)(Alds + (wr * 64 + i * 16 + lr) * GBK + 8 * g);
#pragma unroll
    for (int i = 0; i < 4; ++i)
      bf[i] = *(const s16x8*)(Blds + (wc * 64 + i * 16 + lr) * GBK + 8 * g);
#pragma unroll
    for (int i = 0; i < 4; ++i)
#pragma unroll
      for (int j = 0; j < 4; ++j)
        acc[i][j] = __builtin_amdgcn_mfma_f32_16x16x32_bf16(af[i], bf[j], acc[i][j], 0, 0, 0);
    __syncthreads();
  }
#pragma unroll
  for (int i = 0; i < 4; ++i) {
    int row = m0 + wr * 64 + i * 16 + 4 * g;
#pragma unroll
    for (int j = 0; j < 4; ++j) {
      int col = n0 + wc * 64 + j * 16 + lr;
#pragma unroll
      for (int r = 0; r < 4; ++r) {
        float v = acc[i][j][r];
        if (Cf) Cf[(size_t)(row + r) * N + col] = v;
        else    Cb[(size_t)(row + r) * N + col] = f2bf(v);
      }
    }
  }
}

// ---------------- kvh projection via MFMA -> packed [b][h][n]{k,v} ----------
// grid 128, block 256 (4 waves). Wave w: rows m0+(w&1)*16, cols (w>>1)*16.
// A,B frags loaded directly from global (16B/lane), no LDS.
__global__ __launch_bounds__(256) void kvh_mfma(const unsigned short* __restrict__ X,
                                                const unsigned short* __restrict__ Wb,
                                                float* __restrict__ out) {
  const int tid = threadIdx.x;
  const int wave = tid >> 6, lane = tid & 63;
  const int g = lane >> 4, lr = lane & 15;
  const int rowbase = blockIdx.x * 32 + (wave & 1) * 16;
  const int colbase = (wave >> 1) * 16;

  const unsigned short* xr = X + (size_t)(rowbase + lr) * EE + 8 * g;
  const unsigned short* wr = Wb + (size_t)(colbase + lr) * EE + 8 * g;

  fx4 acc = (fx4){0.f, 0.f, 0.f, 0.f};
#pragma unroll 8
  for (int k0 = 0; k0 < EE; k0 += 32) {
    s16x8 a = *(const s16x8*)(xr + k0);
    s16x8 b = *(const s16x8*)(wr + k0);
    acc = __builtin_amdgcn_mfma_f32_16x16x32_bf16(a, b, acc, 0, 0, 0);
  }
  const int j = colbase + lr;
  const int head = j & 15, sel = j >> 4;
#pragma unroll
  for (int r = 0; r < 4; ++r) {
    int m = rowbase + 4 * g + r;
    int b = m >> 11, n = m & (NN - 1);
    out[(((size_t)(b * HH + head)) * NN + n) * 2 + sel] = acc[r];
  }
}

// ---------------- RoPE on q ((b,n,h,d) -> (b,h,n,d)); input stride NQKV ------
__global__ __launch_bounds__(256) void rope_q(const unsigned short* __restrict__ qp,
                                              unsigned short* __restrict__ qo) {
  int idx = blockIdx.x * 256 + threadIdx.x;
  int i = idx & 63;
  int n = (idx >> 6) & (NN - 1);
  int bh = idx >> 17;
  int b = bh >> 4, h = bh & 15;
  unsigned v = *(const unsigned*)(qp + ((size_t)(b * NN + n) * NQKV + h * DD + 2 * i));
  float x1 = bf2f((unsigned short)(v & 0xffff));
  float x2 = bf2f((unsigned short)(v >> 16));
  float inv = __expf(-0.14391156831212787f * (float)i);
  float ang = (float)n * inv;
  float sn, cs;
  __sincosf(ang, &sn, &cs);
  float o1 = x1 * cs - x2 * sn, o2 = x1 * sn + x2 * cs;
  unsigned ov = ((unsigned)f2bf(o2) << 16) | f2bf(o1);
  *(unsigned*)(qo + ((size_t)bh * NN + n) * DD + 2 * i) = ov;
}

// ---------------- RoPE on shared k (kv cols at NQKV-stride offset 2048) ------
__global__ __launch_bounds__(256) void rope_k(const unsigned short* __restrict__ qkv,
                                              unsigned short* __restrict__ ko) {
  int idx = blockIdx.x * 256 + threadIdx.x;
  int i = idx & 63;
  int bn = idx >> 6;
  int n = bn & (NN - 1);
  unsigned v = *(const unsigned*)(qkv + (size_t)bn * NQKV + 2048 + 2 * i);
  float x1 = bf2f((unsigned short)(v & 0xffff));
  float x2 = bf2f((unsigned short)(v >> 16));
  float inv = __expf(-0.14391156831212787f * (float)i);
  float ang = (float)n * inv;
  float sn, cs;
  __sincosf(ang, &sn, &cs);
  float o1 = x1 * cs - x2 * sn, o2 = x1 * sn + x2 * cs;
  unsigned ov = ((unsigned)f2bf(o2) << 16) | f2bf(o1);
  *(unsigned*)(ko + (size_t)bn * DD + 2 * i) = ov;
}

// ---------------- V transpose: qkv cols 2176..2303 -> vT[b][d][n] ------------
__global__ __launch_bounds__(256) void vtrans(const unsigned short* __restrict__ qkv,
                                              unsigned short* __restrict__ vT) {
  __shared__ unsigned short t[64][40];
  int bx = blockIdx.x;  // 2*4*32 = 256 blocks
  int b = bx >> 7;
  int d0 = ((bx >> 5) & 3) * 32;
  int n0 = (bx & 31) * 64;
  int tid = threadIdx.x;
  {
    int i = tid >> 2;
    int c = (tid & 3) * 8;
    s16x8 v = *(const s16x8*)(qkv + ((size_t)(b * NN + n0 + i)) * NQKV + 2048 + 128 + d0 + c);
#pragma unroll
    for (int u = 0; u < 8; ++u) t[i][c + u] = (unsigned short)v[u];
  }
  __syncthreads();
  {
    int j = tid >> 3;
    int cc = (tid & 7) * 8;
    s16x8 o;
#pragma unroll
    for (int u = 0; u < 8; ++u) o[u] = (short)t[cc + u][j];
    *(s16x8*)(vT + ((size_t)(b * DD + d0 + j)) * NN + n0 + cc) = o;
  }
}

// ---------------- causal flash attention, load-balanced ----------------------
#define QB 64
#define KB 64

__global__ __launch_bounds__(256) void attn(const unsigned short* __restrict__ Q,
                                            const unsigned short* __restrict__ Kr,
                                            const unsigned short* __restrict__ VT,
                                            const float* __restrict__ KVHP,
                                            unsigned short* __restrict__ O) {
  __shared__ alignas(16) unsigned char Klds[64 * 256];
  __shared__ alignas(16) unsigned char Vlds[128 * 128];
  __shared__ alignas(16) unsigned char Plds[4 * 16 * 128];

  const int qp = blockIdx.x;
  const int h = blockIdx.y;
  const int b = blockIdx.z;
  const int tid = threadIdx.x;
  const int wave = tid >> 6, lane = tid & 63;
  const int g = lane >> 4, lr = lane & 15;
  const size_t bh = (size_t)(b * HH + h);

  const float scale2 = 0.08838834764831845f * 1.4426950408889634f;  // exp2 domain
  const unsigned short* Kb = Kr + (size_t)b * NN * DD;
  const unsigned short* VTb = VT + (size_t)b * DD * NN;
  const float2* KVp = (const float2*)KVHP + (size_t)(b * HH + h) * NN;

  for (int half = 0; half < 2; ++half) {
    const int qt = half ? (31 - qp) : qp;
    const int qbase = qt * QB + wave * 16;

    s16x8 qf[4];
    {
      const unsigned short* qptr = Q + (bh * NN + qbase + lr) * DD + 8 * g;
#pragma unroll
      for (int dc = 0; dc < 4; ++dc) qf[dc] = *(const s16x8*)(qptr + dc * 32);
    }

    float m_run[4], l_run[4];
    fx4 oacc[8];
#pragma unroll
    for (int r = 0; r < 4; ++r) { m_run[r] = -1e30f; l_run[r] = 0.f; }
#pragma unroll
    for (int d = 0; d < 8; ++d) oacc[d] = (fx4){0.f, 0.f, 0.f, 0.f};

    const int nkt = qt + 1;
    for (int kt = 0; kt < nkt; ++kt) {
      const int key0 = kt * KB;
      __syncthreads();
#pragma unroll
      for (int j = 0; j < 4; ++j) {
        int rl = wave * 16 + j * 4 + (lane >> 4);
        int ch = (lane & 15) ^ (rl & 7);
        const unsigned char* gp = (const unsigned char*)(Kb + (size_t)(key0 + rl) * DD) + ch * 16;
        gload_lds16(gp, (void*)(Klds + (wave * 16 + j * 4) * 256));
      }
#pragma unroll
      for (int j = 0; j < 4; ++j) {
        int row = wave * 32 + j * 8 + (lane >> 3);
        int c = lane & 7;
        const unsigned short* gp = VTb + (size_t)row * NN + key0 + ((c ^ (row & 7)) * 8);
        gload_lds16(gp, (void*)(Vlds + (wave * 32 + j * 8) * 128));
      }
      float khs[4], vhv[4];
#pragma unroll
      for (int kb = 0; kb < 4; ++kb) {
        float2 kv2 = KVp[key0 + kb * 16 + lr];
        khs[kb] = kv2.x * scale2;
        vhv[kb] = kv2.y;
      }
      __syncthreads();

      fx4 sacc[4];
#pragma unroll
      for (int kb = 0; kb < 4; ++kb) {
        sacc[kb] = (fx4){0.f, 0.f, 0.f, 0.f};
#pragma unroll
        for (int dc = 0; dc < 4; ++dc) {
          int key = kb * 16 + lr;
          int chunk = (dc * 4 + g) ^ (key & 7);
          s16x8 kf = *(const s16x8*)(Klds + key * 256 + chunk * 16);
          sacc[kb] = __builtin_amdgcn_mfma_f32_16x16x32_bf16(qf[dc], kf, sacc[kb], 0, 0, 0);
        }
      }
      float tmax[4];
#pragma unroll
      for (int r = 0; r < 4; ++r) tmax[r] = -1e30f;
      if (kt == qt) {
#pragma unroll
        for (int kb = 0; kb < 4; ++kb) {
          int keyg = key0 + kb * 16 + lr;
#pragma unroll
          for (int r = 0; r < 4; ++r) {
            int qg = qbase + 4 * g + r;
            float s = sacc[kb][r] * khs[kb];
            if (keyg > qg) s = -1e30f;
            sacc[kb][r] = s;
            tmax[r] = fmaxf(tmax[r], s);
          }
        }
      } else {
#pragma unroll
        for (int kb = 0; kb < 4; ++kb) {
#pragma unroll
          for (int r = 0; r < 4; ++r) {
            float s = sacc[kb][r] * khs[kb];
            sacc[kb][r] = s;
            tmax[r] = fmaxf(tmax[r], s);
          }
        }
      }
#pragma unroll
      for (int r = 0; r < 4; ++r) {
        float v = tmax[r];
        v = fmaxf(v, __shfl_xor(v, 1));
        v = fmaxf(v, __shfl_xor(v, 2));
        v = fmaxf(v, __shfl_xor(v, 4));
        v = fmaxf(v, __shfl_xor(v, 8));
        tmax[r] = v;
      }
      float dm = -1e30f;
#pragma unroll
      for (int r = 0; r < 4; ++r) dm = fmaxf(dm, tmax[r] - m_run[r]);
      if (!__all(dm <= 8.0f)) {
        float corr[4];
#pragma unroll
        for (int r = 0; r < 4; ++r) {
          float mnew = fmaxf(m_run[r], tmax[r]);
          corr[r] = exp2f(m_run[r] - mnew);
          m_run[r] = mnew;
          l_run[r] *= corr[r];
        }
#pragma unroll
        for (int d = 0; d < 8; ++d)
#pragma unroll
          for (int r = 0; r < 4; ++r) oacc[d][r] *= corr[r];
      }
      float rsum[4] = {0.f, 0.f, 0.f, 0.f};
#pragma unroll
      for (int kb = 0; kb < 4; ++kb) {
#pragma unroll
        for (int r = 0; r < 4; ++r) {
          float p = exp2f(sacc[kb][r] - m_run[r]);
          rsum[r] += p;
          int ql = 4 * g + r;
          int keyl = kb * 16 + lr;
          int chunk = (keyl >> 3) ^ (ql & 7);
          *(unsigned short*)(Plds + wave * 2048 + ql * 128 + chunk * 16 + (keyl & 7) * 2) =
              f2bf(p * vhv[kb]);
        }
      }
#pragma unroll
      for (int r = 0; r < 4; ++r) {
        float v = rsum[r];
        v += __shfl_xor(v, 1);
        v += __shfl_xor(v, 2);
        v += __shfl_xor(v, 4);
        v += __shfl_xor(v, 8);
        l_run[r] += v;
      }

      s16x8 pa[2];
#pragma unroll
      for (int kk = 0; kk < 2; ++kk) {
        int chunk = (kk * 4 + g) ^ (lr & 7);
        pa[kk] = *(const s16x8*)(Plds + wave * 2048 + lr * 128 + chunk * 16);
      }
#pragma unroll
      for (int dc = 0; dc < 8; ++dc) {
#pragma unroll
        for (int kk = 0; kk < 2; ++kk) {
          int d = dc * 16 + lr;
          int chunk = (kk * 4 + g) ^ (d & 7);
          s16x8 vf = *(const s16x8*)(Vlds + d * 128 + chunk * 16);
          oacc[dc] = __builtin_amdgcn_mfma_f32_16x16x32_bf16(pa[kk], vf, oacc[dc], 0, 0, 0);
        }
      }
    }
#pragma unroll
    for (int r = 0; r < 4; ++r) {
      int qg = qbase + 4 * g + r;
      float inv = 1.0f / l_run[r];
      unsigned short* orow = O + (((size_t)b * NN + qg) * HH + h) * DD;
#pragma unroll
      for (int dc = 0; dc < 8; ++dc) orow[dc * 16 + lr] = f2bf(oacc[dc][r] * inv);
    }
  }
}

// ---------------- launch -----------------------------------------------------
extern "C" void kernel_launch(void* const* d_in, const int* in_sizes, int n_in,
                              void* d_out, int out_size, void* d_ws, size_t ws_size,
                              hipStream_t stream) {
  const float* x = (const float*)d_in[0];
  const float* Wq = (const float*)d_in[1];
  const float* Wkv = (const float*)d_in[2];
  const float* Wkvh = (const float*)d_in[3];
  const float* Wo = (const float*)d_in[4];
  float* out = (float*)d_out;
  char* ws = (char*)d_ws;

  unsigned short* xb    = (unsigned short*)(ws + 0);          // 16 MB (b*n, E)
  unsigned short* obuf  = xb;                                  // alias: x dead by attn
  unsigned short* wqkv  = (unsigned short*)(ws + 16777216);    // 9.4 MB [Wq;Wkv] bf16 (2304 rows)
  unsigned short* vtb   = wqkv;                                // alias: wqkv dead after qkv GEMM
  unsigned short* wob   = (unsigned short*)(ws + 26214400);    // 8 MB
  unsigned short* qkv   = (unsigned short*)(ws + 34603008);    // 18 MB (b*n, 2304)
  unsigned short* wkvhb = (unsigned short*)(ws + 53477376);    // 128 KB Wkvh bf16
  float*          kvhb  = (float*)(ws + 53608448);             // 512 KB packed [b][h][n]{k,v}
  unsigned short* qrope = (unsigned short*)(ws + 54132736);    // 16 MB (b*h, n, d)
  unsigned short* krope = (unsigned short*)(ws + 70909952);    // 512 KB (b*n, d)

  f2b_kernel<<<8192, 256, 0, stream>>>(x, xb, 2097152);
  f2b_kernel<<<4096, 256, 0, stream>>>(Wq, wqkv, 1048576);
  f2b_kernel<<<512, 256, 0, stream>>>(Wkv, wqkv + 4194304, 131072);
  f2b_kernel<<<4096, 256, 0, stream>>>(Wo, wob, 1048576);
  f2b_kernel<<<64, 256, 0, stream>>>(Wkvh, wkvhb, 16384);

  gemm_bt<<<576, 256, 0, stream>>>(xb, wqkv, qkv, (float*)nullptr, 4096, NQKV, 2048);
  kvh_mfma<<<128, 256, 0, stream>>>(xb, wkvhb, kvhb);

  rope_q<<<16384, 256, 0, stream>>>(qkv, qrope);
  rope_k<<<1024, 256, 0, stream>>>(qkv, krope);
  vtrans<<<256, 256, 0, stream>>>(qkv, vtb);

  dim3 ag(16, HH, BB);
  attn<<<ag, 256, 0, stream>>>(qrope, krope, vtb, kvhb, obuf);

  gemm_bt<<<512, 256, 0, stream>>>(obuf, wob, (unsigned short*)nullptr, out, 4096, 2048, 2048);
}

// Round 5
// 261.902 us; speedup vs baseline: 1.9575x; 1.0467x over previous
//
#include <hip/hip_runtime.h>
#include <stdint.h>

#define BB 2
#define HH 16
#define NN 2048
#define DD 128
#define EE 2048
#define NQKV 2304  // 2048 q cols + 256 kv cols

typedef short s16x8 __attribute__((ext_vector_type(8)));
typedef float fx4 __attribute__((ext_vector_type(4)));

static __device__ __forceinline__ unsigned short f2bf(float f) {
  unsigned u = __builtin_bit_cast(unsigned, f);
  u += 0x7fffu + ((u >> 16) & 1u);
  return (unsigned short)(u >> 16);
}
static __device__ __forceinline__ float bf2f(unsigned short h) {
  unsigned u = ((unsigned)h) << 16;
  return __builtin_bit_cast(float, u);
}
static __device__ __forceinline__ void gload_lds16(const void* g, void* l) {
  __builtin_amdgcn_global_load_lds(
      (const __attribute__((address_space(1))) unsigned int*)g,
      (__attribute__((address_space(3))) unsigned int*)l, 16, 0, 0);
}
static __device__ __forceinline__ unsigned cvt_pk_bf16(float lo, float hi) {
  unsigned w;
  asm("v_cvt_pk_bf16_f32 %0, %1, %2" : "=v"(w) : "v"(lo), "v"(hi));
  return w;
}

// ---------------- fp32 -> bf16 convert (vectorized) ----------------
__global__ __launch_bounds__(256) void f2b_kernel(const float* __restrict__ in,
                                                  unsigned short* __restrict__ out,
                                                  int n4) {
  int i = blockIdx.x * 256 + threadIdx.x;
  if (i < n4) {
    float4 v = ((const float4*)in)[i];
    uint2 o;
    o.x = ((unsigned)f2bf(v.y) << 16) | f2bf(v.x);
    o.y = ((unsigned)f2bf(v.w) << 16) | f2bf(v.z);
    ((uint2*)out)[i] = o;
  }
}

// ---------------- NT GEMM: C[m,n] = sum_k A[m,k]*B[n,k] (bf16 in, fp32 acc) --
#define GBM 128
#define GBN 128
#define GBK 32

__global__ __launch_bounds__(256) void gemm_bt(const unsigned short* __restrict__ A,
                                               const unsigned short* __restrict__ B,
                                               unsigned short* __restrict__ Cb,
                                               float* __restrict__ Cf,
                                               int M, int N, int K) {
  __shared__ alignas(16) unsigned short Alds[GBM * GBK];
  __shared__ alignas(16) unsigned short Blds[GBN * GBK];
  const int tid = threadIdx.x;
  const int wave = tid >> 6, lane = tid & 63;
  const int g = lane >> 4, lr = lane & 15;
  const int mtiles = M / GBM;
  const int mt = blockIdx.x % mtiles, nt = blockIdx.x / mtiles;
  const int m0 = mt * GBM, n0 = nt * GBN;
  const int wr = wave >> 1, wc = wave & 1;

  fx4 acc[4][4];
#pragma unroll
  for (int i = 0; i < 4; ++i)
#pragma unroll
    for (int j = 0; j < 4; ++j) acc[i][j] = (fx4){0.f, 0.f, 0.f, 0.f};

  const int srow = wave * 32 + (lane >> 2);
  const int scolb = (lane & 3) * 16;
  const unsigned char* Ag = (const unsigned char*)(A + (size_t)(m0 + srow) * K) + scolb;
  const unsigned char* Bg = (const unsigned char*)(B + (size_t)(n0 + srow) * K) + scolb;
  unsigned short* Al = Alds + wave * 32 * GBK;
  unsigned short* Bl = Blds + wave * 32 * GBK;
  const size_t rowb = (size_t)K * 2;

  for (int k0 = 0; k0 < K; k0 += GBK) {
    const unsigned char* ag = Ag + (size_t)k0 * 2;
    const unsigned char* bg = Bg + (size_t)k0 * 2;
    gload_lds16(ag, Al);
    gload_lds16(ag + 16 * rowb, Al + 16 * GBK);
    gload_lds16(bg, Bl);
    gload_lds16(bg + 16 * rowb, Bl + 16 * GBK);
    __syncthreads();
    s16x8 af[4], bf[4];
#pragma unroll
    for (int i = 0; i < 4; ++i)
      af[i] = *(const s16x8*)(Alds + (wr * 64 + i * 16 + lr) * GBK + 8 * g);
#pragma unroll
    for (int i = 0; i < 4; ++i)
      bf[i] = *(const s16x8*)(Blds + (wc * 64 + i * 16 + lr) * GBK + 8 * g);
#pragma unroll
    for (int i = 0; i < 4; ++i)
#pragma unroll
      for (int j = 0; j < 4; ++j)
        acc[i][j] = __builtin_amdgcn_mfma_f32_16x16x32_bf16(af[i], bf[j], acc[i][j], 0, 0, 0);
    __syncthreads();
  }
#pragma unroll
  for (int i = 0; i < 4; ++i) {
    int row = m0 + wr * 64 + i * 16 + 4 * g;
#pragma unroll
    for (int j = 0; j < 4; ++j) {
      int col = n0 + wc * 64 + j * 16 + lr;
#pragma unroll
      for (int r = 0; r < 4; ++r) {
        float v = acc[i][j][r];
        if (Cf) Cf[(size_t)(row + r) * N + col] = v;
        else    Cb[(size_t)(row + r) * N + col] = f2bf(v);
      }
    }
  }
}

// ---------------- kvh projection via MFMA -> packed [b][h][n]{k,v} ----------
__global__ __launch_bounds__(256) void kvh_mfma(const unsigned short* __restrict__ X,
                                                const unsigned short* __restrict__ Wb,
                                                float* __restrict__ out) {
  const int tid = threadIdx.x;
  const int wave = tid >> 6, lane = tid & 63;
  const int g = lane >> 4, lr = lane & 15;
  const int rowbase = blockIdx.x * 32 + (wave & 1) * 16;
  const int colbase = (wave >> 1) * 16;

  const unsigned short* xr = X + (size_t)(rowbase + lr) * EE + 8 * g;
  const unsigned short* wr = Wb + (size_t)(colbase + lr) * EE + 8 * g;

  fx4 acc = (fx4){0.f, 0.f, 0.f, 0.f};
#pragma unroll 8
  for (int k0 = 0; k0 < EE; k0 += 32) {
    s16x8 a = *(const s16x8*)(xr + k0);
    s16x8 b = *(const s16x8*)(wr + k0);
    acc = __builtin_amdgcn_mfma_f32_16x16x32_bf16(a, b, acc, 0, 0, 0);
  }
  const int j = colbase + lr;
  const int head = j & 15, sel = j >> 4;
#pragma unroll
  for (int r = 0; r < 4; ++r) {
    int m = rowbase + 4 * g + r;
    int b = m >> 11, n = m & (NN - 1);
    out[(((size_t)(b * HH + head)) * NN + n) * 2 + sel] = acc[r];
  }
}

// ---------------- RoPE on q ((b,n,h,d) -> (b,h,n,d)); input stride NQKV ------
__global__ __launch_bounds__(256) void rope_q(const unsigned short* __restrict__ qp,
                                              unsigned short* __restrict__ qo) {
  int idx = blockIdx.x * 256 + threadIdx.x;
  int i = idx & 63;
  int n = (idx >> 6) & (NN - 1);
  int bh = idx >> 17;
  int b = bh >> 4, h = bh & 15;
  unsigned v = *(const unsigned*)(qp + ((size_t)(b * NN + n) * NQKV + h * DD + 2 * i));
  float x1 = bf2f((unsigned short)(v & 0xffff));
  float x2 = bf2f((unsigned short)(v >> 16));
  float inv = __expf(-0.14391156831212787f * (float)i);
  float ang = (float)n * inv;
  float sn, cs;
  __sincosf(ang, &sn, &cs);
  float o1 = x1 * cs - x2 * sn, o2 = x1 * sn + x2 * cs;
  unsigned ov = ((unsigned)f2bf(o2) << 16) | f2bf(o1);
  *(unsigned*)(qo + ((size_t)bh * NN + n) * DD + 2 * i) = ov;
}

// ---------------- RoPE on shared k (kv cols at NQKV-stride offset 2048) ------
__global__ __launch_bounds__(256) void rope_k(const unsigned short* __restrict__ qkv,
                                              unsigned short* __restrict__ ko) {
  int idx = blockIdx.x * 256 + threadIdx.x;
  int i = idx & 63;
  int bn = idx >> 6;
  int n = bn & (NN - 1);
  unsigned v = *(const unsigned*)(qkv + (size_t)bn * NQKV + 2048 + 2 * i);
  float x1 = bf2f((unsigned short)(v & 0xffff));
  float x2 = bf2f((unsigned short)(v >> 16));
  float inv = __expf(-0.14391156831212787f * (float)i);
  float ang = (float)n * inv;
  float sn, cs;
  __sincosf(ang, &sn, &cs);
  float o1 = x1 * cs - x2 * sn, o2 = x1 * sn + x2 * cs;
  unsigned ov = ((unsigned)f2bf(o2) << 16) | f2bf(o1);
  *(unsigned*)(ko + (size_t)bn * DD + 2 * i) = ov;
}

// ---------------- V transpose: qkv cols 2176..2303 -> vT[b][d][n] ------------
__global__ __launch_bounds__(256) void vtrans(const unsigned short* __restrict__ qkv,
                                              unsigned short* __restrict__ vT) {
  __shared__ unsigned short t[64][40];
  int bx = blockIdx.x;  // 2*4*32 = 256 blocks
  int b = bx >> 7;
  int d0 = ((bx >> 5) & 3) * 32;
  int n0 = (bx & 31) * 64;
  int tid = threadIdx.x;
  {
    int i = tid >> 2;
    int c = (tid & 3) * 8;
    s16x8 v = *(const s16x8*)(qkv + ((size_t)(b * NN + n0 + i)) * NQKV + 2048 + 128 + d0 + c);
#pragma unroll
    for (int u = 0; u < 8; ++u) t[i][c + u] = (unsigned short)v[u];
  }
  __syncthreads();
  {
    int j = tid >> 3;
    int cc = (tid & 7) * 8;
    s16x8 o;
#pragma unroll
    for (int u = 0; u < 8; ++u) o[u] = (short)t[cc + u][j];
    *(s16x8*)(vT + ((size_t)(b * DD + d0 + j)) * NN + n0 + cc) = o;
  }
}

// ---------------- causal flash attention, swapped-QK^T (T12) -----------------
// grid (16 qpairs, 16 h, 2 b); block = 4 waves x 16 q-rows; KBLK=64.
// QK^T computed as mfma(K,Q): lane holds S[key=4g+r][q=lr] -> per-lane q-row,
// packed b64 P-stores, scalar m/l, 4 shuffles/tile.
#define QB 64
#define KB 64

__global__ __launch_bounds__(256) void attn(const unsigned short* __restrict__ Q,
                                            const unsigned short* __restrict__ Kr,
                                            const unsigned short* __restrict__ VT,
                                            const float* __restrict__ KVHP,
                                            unsigned short* __restrict__ O) {
  __shared__ alignas(16) unsigned char Klds[64 * 256];    // [key][d], chunk^=(key&7)
  __shared__ alignas(16) unsigned char Vlds[128 * 128];   // [d][key], chunk^=(d&7)
  __shared__ alignas(16) unsigned char Plds[4 * 16 * 128];// per-wave [q][key], chunk^=(q&7)

  const int qp = blockIdx.x;
  const int h = blockIdx.y;
  const int b = blockIdx.z;
  const int tid = threadIdx.x;
  const int wave = tid >> 6, lane = tid & 63;
  const int g = lane >> 4, lr = lane & 15;
  const size_t bh = (size_t)(b * HH + h);

  const float scale2 = 0.08838834764831845f * 1.4426950408889634f;  // exp2 domain
  const unsigned short* Kb = Kr + (size_t)b * NN * DD;
  const unsigned short* VTb = VT + (size_t)b * DD * NN;
  const float2* KVp = (const float2*)KVHP + (size_t)(b * HH + h) * NN;

  for (int half = 0; half < 2; ++half) {
    const int qt = half ? (31 - qp) : qp;
    const int qbase = qt * QB + wave * 16;
    const int qg = qbase + lr;  // this lane's q row

    s16x8 qf[4];
    {
      const unsigned short* qptr = Q + (bh * NN + qbase + lr) * DD + 8 * g;
#pragma unroll
      for (int dc = 0; dc < 4; ++dc) qf[dc] = *(const s16x8*)(qptr + dc * 32);
    }

    float m_run = -1e30f, l_run = 0.f;
    fx4 oacc[8];
#pragma unroll
    for (int d = 0; d < 8; ++d) oacc[d] = (fx4){0.f, 0.f, 0.f, 0.f};

    const int nkt = qt + 1;
    for (int kt = 0; kt < nkt; ++kt) {
      const int key0 = kt * KB;
      __syncthreads();
      // --- stage K (global_load_lds, pre-swizzled source) ---
#pragma unroll
      for (int j = 0; j < 4; ++j) {
        int rl = wave * 16 + j * 4 + (lane >> 4);
        int ch = (lane & 15) ^ (rl & 7);
        const unsigned char* gp = (const unsigned char*)(Kb + (size_t)(key0 + rl) * DD) + ch * 16;
        gload_lds16(gp, (void*)(Klds + (wave * 16 + j * 4) * 256));
      }
      // --- stage V^T (global_load_lds from pre-transposed vT, swizzled src) ---
#pragma unroll
      for (int j = 0; j < 4; ++j) {
        int row = wave * 32 + j * 8 + (lane >> 3);
        int c = lane & 7;
        const unsigned short* gp = VTb + (size_t)row * NN + key0 + ((c ^ (row & 7)) * 8);
        gload_lds16(gp, (void*)(Vlds + (wave * 32 + j * 8) * 128));
      }
      // --- head scales for this lane's 4 keys per kb (float4-pair loads) ---
      fx4 khv[4], vhv[4];
#pragma unroll
      for (int kb = 0; kb < 4; ++kb) {
        const float4* kp = (const float4*)(KVp + key0 + kb * 16 + 4 * g);
        float4 f0 = kp[0];  // k0 v0 k1 v1
        float4 f1 = kp[1];  // k2 v2 k3 v3
        khv[kb] = (fx4){f0.x * scale2, f0.z * scale2, f1.x * scale2, f1.z * scale2};
        vhv[kb] = (fx4){f0.y, f0.w, f1.y, f1.w};
      }
      __syncthreads();

      // --- QK^T swapped: sacc[kb][r] = S[key=key0+kb*16+4g+r][q=lr] ---
      fx4 sacc[4];
#pragma unroll
      for (int kb = 0; kb < 4; ++kb) {
        sacc[kb] = (fx4){0.f, 0.f, 0.f, 0.f};
#pragma unroll
        for (int dc = 0; dc < 4; ++dc) {
          int key = kb * 16 + lr;
          int chunk = (dc * 4 + g) ^ (key & 7);
          s16x8 kf = *(const s16x8*)(Klds + key * 256 + chunk * 16);
          sacc[kb] = __builtin_amdgcn_mfma_f32_16x16x32_bf16(kf, qf[dc], sacc[kb], 0, 0, 0);
        }
      }
      // --- scale by khead, mask (diag only), per-lane max over 16 keys ---
      float smax = -1e30f;
      if (kt == qt) {
#pragma unroll
        for (int kb = 0; kb < 4; ++kb) {
#pragma unroll
          for (int r = 0; r < 4; ++r) {
            int keyg = key0 + kb * 16 + 4 * g + r;
            float s = sacc[kb][r] * khv[kb][r];
            if (keyg > qg) s = -1e30f;
            sacc[kb][r] = s;
            smax = fmaxf(smax, s);
          }
        }
      } else {
#pragma unroll
        for (int kb = 0; kb < 4; ++kb) {
#pragma unroll
          for (int r = 0; r < 4; ++r) {
            float s = sacc[kb][r] * khv[kb][r];
            sacc[kb][r] = s;
            smax = fmaxf(smax, s);
          }
        }
      }
      // cross-lane max over the 4 lanes holding the same q (xor 16, 32)
      smax = fmaxf(smax, __shfl_xor(smax, 16));
      smax = fmaxf(smax, __shfl_xor(smax, 32));
      // --- T13 defer-rescale ---
      if (!__all(smax - m_run <= 8.0f)) {
        float mnew = fmaxf(m_run, smax);
        float corr = exp2f(m_run - mnew);
        m_run = mnew;
        l_run *= corr;
        float cr[4];
#pragma unroll
        for (int r = 0; r < 4; ++r) cr[r] = __shfl(corr, 4 * g + r);
#pragma unroll
        for (int d = 0; d < 8; ++d)
#pragma unroll
          for (int r = 0; r < 4; ++r) oacc[d][r] *= cr[r];
      }
      // --- P = exp2(s - m), fold vhead, pack to bf16, b64 store ---
      float rsum = 0.f;
#pragma unroll
      for (int kb = 0; kb < 4; ++kb) {
        float p0 = exp2f(sacc[kb][0] - m_run);
        float p1 = exp2f(sacc[kb][1] - m_run);
        float p2 = exp2f(sacc[kb][2] - m_run);
        float p3 = exp2f(sacc[kb][3] - m_run);
        rsum += (p0 + p1) + (p2 + p3);
        uint2 w;
        w.x = cvt_pk_bf16(p0 * vhv[kb][0], p1 * vhv[kb][1]);
        w.y = cvt_pk_bf16(p2 * vhv[kb][2], p3 * vhv[kb][3]);
        int chunk = (kb * 2 + (g >> 1)) ^ (lr & 7);
        *(uint2*)(Plds + wave * 2048 + lr * 128 + chunk * 16 + (g & 1) * 8) = w;
      }
      rsum += __shfl_xor(rsum, 16);
      rsum += __shfl_xor(rsum, 32);
      l_run += rsum;

      // --- PV (unchanged) ---
      s16x8 pa[2];
#pragma unroll
      for (int kk = 0; kk < 2; ++kk) {
        int chunk = (kk * 4 + g) ^ (lr & 7);
        pa[kk] = *(const s16x8*)(Plds + wave * 2048 + lr * 128 + chunk * 16);
      }
#pragma unroll
      for (int dc = 0; dc < 8; ++dc) {
#pragma unroll
        for (int kk = 0; kk < 2; ++kk) {
          int d = dc * 16 + lr;
          int chunk = (kk * 4 + g) ^ (d & 7);
          s16x8 vf = *(const s16x8*)(Vlds + d * 128 + chunk * 16);
          oacc[dc] = __builtin_amdgcn_mfma_f32_16x16x32_bf16(pa[kk], vf, oacc[dc], 0, 0, 0);
        }
      }
    }
    // --- epilogue: fetch 1/l for q=4g+r via shfl, store O[b,n,h,d] ---
    float inv = 1.0f / l_run;
#pragma unroll
    for (int r = 0; r < 4; ++r) {
      float invr = __shfl(inv, 4 * g + r);
      int qout = qbase + 4 * g + r;
      unsigned short* orow = O + (((size_t)b * NN + qout) * HH + h) * DD;
#pragma unroll
      for (int dc = 0; dc < 8; ++dc) orow[dc * 16 + lr] = f2bf(oacc[dc][r] * invr);
    }
  }
}

// ---------------- launch -----------------------------------------------------
extern "C" void kernel_launch(void* const* d_in, const int* in_sizes, int n_in,
                              void* d_out, int out_size, void* d_ws, size_t ws_size,
                              hipStream_t stream) {
  const float* x = (const float*)d_in[0];
  const float* Wq = (const float*)d_in[1];
  const float* Wkv = (const float*)d_in[2];
  const float* Wkvh = (const float*)d_in[3];
  const float* Wo = (const float*)d_in[4];
  float* out = (float*)d_out;
  char* ws = (char*)d_ws;

  unsigned short* xb    = (unsigned short*)(ws + 0);          // 16 MB (b*n, E)
  unsigned short* obuf  = xb;                                  // alias: x dead by attn
  unsigned short* wqkv  = (unsigned short*)(ws + 16777216);    // 9.4 MB [Wq;Wkv] bf16
  unsigned short* vtb   = wqkv;                                // alias: wqkv dead after qkv GEMM
  unsigned short* wob   = (unsigned short*)(ws + 26214400);    // 8 MB
  unsigned short* qkv   = (unsigned short*)(ws + 34603008);    // 18 MB (b*n, 2304)
  unsigned short* wkvhb = (unsigned short*)(ws + 53477376);    // 128 KB Wkvh bf16
  float*          kvhb  = (float*)(ws + 53608448);             // 512 KB packed [b][h][n]{k,v}
  unsigned short* qrope = (unsigned short*)(ws + 54132736);    // 16 MB (b*h, n, d)
  unsigned short* krope = (unsigned short*)(ws + 70909952);    // 512 KB (b*n, d)

  f2b_kernel<<<8192, 256, 0, stream>>>(x, xb, 2097152);
  f2b_kernel<<<4096, 256, 0, stream>>>(Wq, wqkv, 1048576);
  f2b_kernel<<<512, 256, 0, stream>>>(Wkv, wqkv + 4194304, 131072);
  f2b_kernel<<<4096, 256, 0, stream>>>(Wo, wob, 1048576);
  f2b_kernel<<<64, 256, 0, stream>>>(Wkvh, wkvhb, 16384);

  gemm_bt<<<576, 256, 0, stream>>>(xb, wqkv, qkv, (float*)nullptr, 4096, NQKV, 2048);
  kvh_mfma<<<128, 256, 0, stream>>>(xb, wkvhb, kvhb);

  rope_q<<<16384, 256, 0, stream>>>(qkv, qrope);
  rope_k<<<1024, 256, 0, stream>>>(qkv, krope);
  vtrans<<<256, 256, 0, stream>>>(qkv, vtb);

  dim3 ag(16, HH, BB);
  attn<<<ag, 256, 0, stream>>>(qrope, krope, vtb, kvhb, obuf);

  gemm_bt<<<512, 256, 0, stream>>>(obuf, wob, (unsigned short*)nullptr, out, 4096, 2048, 2048);
}

// Round 6
// 256.239 us; speedup vs baseline: 2.0007x; 1.0221x over previous
//
#include <hip/hip_runtime.h>
#include <stdint.h>

#define BB 2
#define HH 16
#define NN 2048
#define DD 128
#define EE 2048
#define NQKV 2304  // 2048 q cols + 256 kv cols

typedef short s16x8 __attribute__((ext_vector_type(8)));
typedef float fx4 __attribute__((ext_vector_type(4)));

static __device__ __forceinline__ unsigned short f2bf(float f) {
  unsigned u = __builtin_bit_cast(unsigned, f);
  u += 0x7fffu + ((u >> 16) & 1u);
  return (unsigned short)(u >> 16);
}
static __device__ __forceinline__ float bf2f(unsigned short h) {
  unsigned u = ((unsigned)h) << 16;
  return __builtin_bit_cast(float, u);
}
static __device__ __forceinline__ void gload_lds16(const void* g, void* l) {
  __builtin_amdgcn_global_load_lds(
      (const __attribute__((address_space(1))) unsigned int*)g,
      (__attribute__((address_space(3))) unsigned int*)l, 16, 0, 0);
}
static __device__ __forceinline__ unsigned cvt_pk_bf16(float lo, float hi) {
  unsigned w;
  asm("v_cvt_pk_bf16_f32 %0, %1, %2" : "=v"(w) : "v"(lo), "v"(hi));
  return w;
}

// ---------------- fp32 -> bf16 convert (vectorized) ----------------
__global__ __launch_bounds__(256) void f2b_kernel(const float* __restrict__ in,
                                                  unsigned short* __restrict__ out,
                                                  int n4) {
  int i = blockIdx.x * 256 + threadIdx.x;
  if (i < n4) {
    float4 v = ((const float4*)in)[i];
    uint2 o;
    o.x = ((unsigned)f2bf(v.y) << 16) | f2bf(v.x);
    o.y = ((unsigned)f2bf(v.w) << 16) | f2bf(v.z);
    ((uint2*)out)[i] = o;
  }
}

// ---------------- NT GEMM: C[m,n] = sum_k A[m,k]*B[n,k] (bf16 in, fp32 acc) --
#define GBM 128
#define GBN 128
#define GBK 32

__global__ __launch_bounds__(256) void gemm_bt(const unsigned short* __restrict__ A,
                                               const unsigned short* __restrict__ B,
                                               unsigned short* __restrict__ Cb,
                                               float* __restrict__ Cf,
                                               int M, int N, int K) {
  __shared__ alignas(16) unsigned short Alds[GBM * GBK];
  __shared__ alignas(16) unsigned short Blds[GBN * GBK];
  const int tid = threadIdx.x;
  const int wave = tid >> 6, lane = tid & 63;
  const int g = lane >> 4, lr = lane & 15;
  const int mtiles = M / GBM;
  const int mt = blockIdx.x % mtiles, nt = blockIdx.x / mtiles;
  const int m0 = mt * GBM, n0 = nt * GBN;
  const int wr = wave >> 1, wc = wave & 1;

  fx4 acc[4][4];
#pragma unroll
  for (int i = 0; i < 4; ++i)
#pragma unroll
    for (int j = 0; j < 4; ++j) acc[i][j] = (fx4){0.f, 0.f, 0.f, 0.f};

  const int srow = wave * 32 + (lane >> 2);
  const int scolb = (lane & 3) * 16;
  const unsigned char* Ag = (const unsigned char*)(A + (size_t)(m0 + srow) * K) + scolb;
  const unsigned char* Bg = (const unsigned char*)(B + (size_t)(n0 + srow) * K) + scolb;
  unsigned short* Al = Alds + wave * 32 * GBK;
  unsigned short* Bl = Blds + wave * 32 * GBK;
  const size_t rowb = (size_t)K * 2;

  for (int k0 = 0; k0 < K; k0 += GBK) {
    const unsigned char* ag = Ag + (size_t)k0 * 2;
    const unsigned char* bg = Bg + (size_t)k0 * 2;
    gload_lds16(ag, Al);
    gload_lds16(ag + 16 * rowb, Al + 16 * GBK);
    gload_lds16(bg, Bl);
    gload_lds16(bg + 16 * rowb, Bl + 16 * GBK);
    __syncthreads();
    s16x8 af[4], bf[4];
#pragma unroll
    for (int i = 0; i < 4; ++i)
      af[i] = *(const s16x8*)(Alds + (wr * 64 + i * 16 + lr) * GBK + 8 * g);
#pragma unroll
    for (int i = 0; i < 4; ++i)
      bf[i] = *(const s16x8*)(Blds + (wc * 64 + i * 16 + lr) * GBK + 8 * g);
#pragma unroll
    for (int i = 0; i < 4; ++i)
#pragma unroll
      for (int j = 0; j < 4; ++j)
        acc[i][j] = __builtin_amdgcn_mfma_f32_16x16x32_bf16(af[i], bf[j], acc[i][j], 0, 0, 0);
    __syncthreads();
  }
#pragma unroll
  for (int i = 0; i < 4; ++i) {
    int row = m0 + wr * 64 + i * 16 + 4 * g;
#pragma unroll
    for (int j = 0; j < 4; ++j) {
      int col = n0 + wc * 64 + j * 16 + lr;
#pragma unroll
      for (int r = 0; r < 4; ++r) {
        float v = acc[i][j][r];
        if (Cf) Cf[(size_t)(row + r) * N + col] = v;
        else    Cb[(size_t)(row + r) * N + col] = f2bf(v);
      }
    }
  }
}

// ---------------- kvh projection via MFMA -> packed [b][h][n]{k,v} ----------
__global__ __launch_bounds__(256) void kvh_mfma(const unsigned short* __restrict__ X,
                                                const unsigned short* __restrict__ Wb,
                                                float* __restrict__ out) {
  const int tid = threadIdx.x;
  const int wave = tid >> 6, lane = tid & 63;
  const int g = lane >> 4, lr = lane & 15;
  const int rowbase = blockIdx.x * 32 + (wave & 1) * 16;
  const int colbase = (wave >> 1) * 16;

  const unsigned short* xr = X + (size_t)(rowbase + lr) * EE + 8 * g;
  const unsigned short* wr = Wb + (size_t)(colbase + lr) * EE + 8 * g;

  fx4 acc = (fx4){0.f, 0.f, 0.f, 0.f};
#pragma unroll 8
  for (int k0 = 0; k0 < EE; k0 += 32) {
    s16x8 a = *(const s16x8*)(xr + k0);
    s16x8 b = *(const s16x8*)(wr + k0);
    acc = __builtin_amdgcn_mfma_f32_16x16x32_bf16(a, b, acc, 0, 0, 0);
  }
  const int j = colbase + lr;
  const int head = j & 15, sel = j >> 4;
#pragma unroll
  for (int r = 0; r < 4; ++r) {
    int m = rowbase + 4 * g + r;
    int b = m >> 11, n = m & (NN - 1);
    out[(((size_t)(b * HH + head)) * NN + n) * 2 + sel] = acc[r];
  }
}

// ---------------- RoPE on q ((b,n,h,d) -> (b,h,n,d)); input stride NQKV ------
__global__ __launch_bounds__(256) void rope_q(const unsigned short* __restrict__ qp,
                                              unsigned short* __restrict__ qo) {
  int idx = blockIdx.x * 256 + threadIdx.x;
  int i = idx & 63;
  int n = (idx >> 6) & (NN - 1);
  int bh = idx >> 17;
  int b = bh >> 4, h = bh & 15;
  unsigned v = *(const unsigned*)(qp + ((size_t)(b * NN + n) * NQKV + h * DD + 2 * i));
  float x1 = bf2f((unsigned short)(v & 0xffff));
  float x2 = bf2f((unsigned short)(v >> 16));
  float inv = __expf(-0.14391156831212787f * (float)i);
  float ang = (float)n * inv;
  float sn, cs;
  __sincosf(ang, &sn, &cs);
  float o1 = x1 * cs - x2 * sn, o2 = x1 * sn + x2 * cs;
  unsigned ov = ((unsigned)f2bf(o2) << 16) | f2bf(o1);
  *(unsigned*)(qo + ((size_t)bh * NN + n) * DD + 2 * i) = ov;
}

// ---------------- RoPE on shared k (kv cols at NQKV-stride offset 2048) ------
__global__ __launch_bounds__(256) void rope_k(const unsigned short* __restrict__ qkv,
                                              unsigned short* __restrict__ ko) {
  int idx = blockIdx.x * 256 + threadIdx.x;
  int i = idx & 63;
  int bn = idx >> 6;
  int n = bn & (NN - 1);
  unsigned v = *(const unsigned*)(qkv + (size_t)bn * NQKV + 2048 + 2 * i);
  float x1 = bf2f((unsigned short)(v & 0xffff));
  float x2 = bf2f((unsigned short)(v >> 16));
  float inv = __expf(-0.14391156831212787f * (float)i);
  float ang = (float)n * inv;
  float sn, cs;
  __sincosf(ang, &sn, &cs);
  float o1 = x1 * cs - x2 * sn, o2 = x1 * sn + x2 * cs;
  unsigned ov = ((unsigned)f2bf(o2) << 16) | f2bf(o1);
  *(unsigned*)(ko + (size_t)bn * DD + 2 * i) = ov;
}

// ---------------- V transpose: qkv cols 2176..2303 -> vT[b][d][n] ------------
__global__ __launch_bounds__(256) void vtrans(const unsigned short* __restrict__ qkv,
                                              unsigned short* __restrict__ vT) {
  __shared__ unsigned short t[64][40];
  int bx = blockIdx.x;  // 2*4*32 = 256 blocks
  int b = bx >> 7;
  int d0 = ((bx >> 5) & 3) * 32;
  int n0 = (bx & 31) * 64;
  int tid = threadIdx.x;
  {
    int i = tid >> 2;
    int c = (tid & 3) * 8;
    s16x8 v = *(const s16x8*)(qkv + ((size_t)(b * NN + n0 + i)) * NQKV + 2048 + 128 + d0 + c);
#pragma unroll
    for (int u = 0; u < 8; ++u) t[i][c + u] = (unsigned short)v[u];
  }
  __syncthreads();
  {
    int j = tid >> 3;
    int cc = (tid & 7) * 8;
    s16x8 o;
#pragma unroll
    for (int u = 0; u < 8; ++u) o[u] = (short)t[cc + u][j];
    *(s16x8*)(vT + ((size_t)(b * DD + d0 + j)) * NN + n0 + cc) = o;
  }
}

// ---------------- causal flash attention, swapped-QK^T + K/V double-buffer ---
// grid (16 qpairs, 16 h, 2 b); block = 4 waves x 16 q-rows; KBLK=64.
// 2-deep pipeline: issue khv loads, STAGE(next->buf^1), vmcnt(16), raw barrier.
// Never vmcnt(0) in the loop (T3/T4/T14).
#define QB 64
#define KB 64

__global__ __launch_bounds__(256) void attn(const unsigned short* __restrict__ Q,
                                            const unsigned short* __restrict__ Kr,
                                            const unsigned short* __restrict__ VT,
                                            const float* __restrict__ KVHP,
                                            unsigned short* __restrict__ O) {
  __shared__ alignas(16) unsigned char Klds[2][64 * 256];    // [key][d], chunk^=(key&7)
  __shared__ alignas(16) unsigned char Vlds[2][128 * 128];   // [d][key], chunk^=(d&7)
  __shared__ alignas(16) unsigned char Plds[4 * 16 * 128];   // per-wave [q][key]

  const int qp = blockIdx.x;
  const int h = blockIdx.y;
  const int b = blockIdx.z;
  const int tid = threadIdx.x;
  const int wave = tid >> 6, lane = tid & 63;
  const int g = lane >> 4, lr = lane & 15;
  const size_t bh = (size_t)(b * HH + h);

  const float scale2 = 0.08838834764831845f * 1.4426950408889634f;  // exp2 domain
  const unsigned short* Kb = Kr + (size_t)b * NN * DD;
  const unsigned short* VTb = VT + (size_t)b * DD * NN;
  const float2* KVp = (const float2*)KVHP + (size_t)(b * HH + h) * NN;

  // cooperative stage of one K/V tile into buffer bi (8 gload_lds per lane)
  auto STAGE = [&](int bi, int key0s) {
    unsigned char* Kl = Klds[bi];
    unsigned char* Vl = Vlds[bi];
#pragma unroll
    for (int j = 0; j < 4; ++j) {
      int rl = wave * 16 + j * 4 + (lane >> 4);
      int ch = (lane & 15) ^ (rl & 7);
      const unsigned char* gp = (const unsigned char*)(Kb + (size_t)(key0s + rl) * DD) + ch * 16;
      gload_lds16(gp, (void*)(Kl + (wave * 16 + j * 4) * 256));
    }
#pragma unroll
    for (int j = 0; j < 4; ++j) {
      int row = wave * 32 + j * 8 + (lane >> 3);
      int c = lane & 7;
      const unsigned short* gp = VTb + (size_t)row * NN + key0s + ((c ^ (row & 7)) * 8);
      gload_lds16(gp, (void*)(Vl + (wave * 32 + j * 8) * 128));
    }
  };

  for (int half = 0; half < 2; ++half) {
    const int qt = half ? (31 - qp) : qp;
    const int qbase = qt * QB + wave * 16;
    const int qg = qbase + lr;  // this lane's q row

    s16x8 qf[4];
    {
      const unsigned short* qptr = Q + (bh * NN + qbase + lr) * DD + 8 * g;
#pragma unroll
      for (int dc = 0; dc < 4; ++dc) qf[dc] = *(const s16x8*)(qptr + dc * 32);
    }

    float m_run = -1e30f, l_run = 0.f;
    fx4 oacc[8];
#pragma unroll
    for (int d = 0; d < 8; ++d) oacc[d] = (fx4){0.f, 0.f, 0.f, 0.f};

    const int nkt = qt + 1;
    STAGE(0, 0);  // prologue: tile 0 -> buf0

    for (int kt = 0; kt < nkt; ++kt) {
      const int key0 = kt * KB;
      const int cur = kt & 1;

      // --- khv/vhv loads FIRST (so their use-wait doesn't drain the prefetch)
      fx4 khv[4], vhv[4];
#pragma unroll
      for (int kb = 0; kb < 4; ++kb) {
        const float4* kp = (const float4*)(KVp + key0 + kb * 16 + 4 * g);
        float4 f0 = kp[0];  // k0 v0 k1 v1
        float4 f1 = kp[1];  // k2 v2 k3 v3
        khv[kb] = (fx4){f0.x * scale2, f0.z * scale2, f1.x * scale2, f1.z * scale2};
        vhv[kb] = (fx4){f0.y, f0.w, f1.y, f1.w};
      }
      // --- STAGE next tile into buf^1 (clamped dummy on last iter: uniform count)
      {
        int nkey = (kt + 1 < nkt) ? key0 + KB : key0;
        STAGE(cur ^ 1, nkey);
      }
      // --- wait for CURRENT tile's stage (8 khv + 8 next-stage may stay in flight)
      asm volatile("s_waitcnt vmcnt(16)" ::: "memory");
      __builtin_amdgcn_s_barrier();
      __builtin_amdgcn_sched_barrier(0);

      const unsigned char* Kl = Klds[cur];
      const unsigned char* Vl = Vlds[cur];

      // --- QK^T swapped: sacc[kb][r] = S[key=key0+kb*16+4g+r][q=lr] ---
      fx4 sacc[4];
#pragma unroll
      for (int kb = 0; kb < 4; ++kb) {
        sacc[kb] = (fx4){0.f, 0.f, 0.f, 0.f};
#pragma unroll
        for (int dc = 0; dc < 4; ++dc) {
          int key = kb * 16 + lr;
          int chunk = (dc * 4 + g) ^ (key & 7);
          s16x8 kf = *(const s16x8*)(Kl + key * 256 + chunk * 16);
          sacc[kb] = __builtin_amdgcn_mfma_f32_16x16x32_bf16(kf, qf[dc], sacc[kb], 0, 0, 0);
        }
      }
      // --- scale by khead, mask (diag only), per-lane max over 16 keys ---
      float smax = -1e30f;
      if (kt == qt) {
#pragma unroll
        for (int kb = 0; kb < 4; ++kb) {
#pragma unroll
          for (int r = 0; r < 4; ++r) {
            int keyg = key0 + kb * 16 + 4 * g + r;
            float s = sacc[kb][r] * khv[kb][r];
            if (keyg > qg) s = -1e30f;
            sacc[kb][r] = s;
            smax = fmaxf(smax, s);
          }
        }
      } else {
#pragma unroll
        for (int kb = 0; kb < 4; ++kb) {
#pragma unroll
          for (int r = 0; r < 4; ++r) {
            float s = sacc[kb][r] * khv[kb][r];
            sacc[kb][r] = s;
            smax = fmaxf(smax, s);
          }
        }
      }
      // cross-lane max over the 4 lanes holding the same q (xor 16, 32)
      smax = fmaxf(smax, __shfl_xor(smax, 16));
      smax = fmaxf(smax, __shfl_xor(smax, 32));
      // --- T13 defer-rescale ---
      if (!__all(smax - m_run <= 8.0f)) {
        float mnew = fmaxf(m_run, smax);
        float corr = exp2f(m_run - mnew);
        m_run = mnew;
        l_run *= corr;
        float cr[4];
#pragma unroll
        for (int r = 0; r < 4; ++r) cr[r] = __shfl(corr, 4 * g + r);
#pragma unroll
        for (int d = 0; d < 8; ++d)
#pragma unroll
          for (int r = 0; r < 4; ++r) oacc[d][r] *= cr[r];
      }
      // --- P = exp2(s - m), fold vhead, pack to bf16, b64 store ---
      float rsum = 0.f;
#pragma unroll
      for (int kb = 0; kb < 4; ++kb) {
        float p0 = exp2f(sacc[kb][0] - m_run);
        float p1 = exp2f(sacc[kb][1] - m_run);
        float p2 = exp2f(sacc[kb][2] - m_run);
        float p3 = exp2f(sacc[kb][3] - m_run);
        rsum += (p0 + p1) + (p2 + p3);
        uint2 w;
        w.x = cvt_pk_bf16(p0 * vhv[kb][0], p1 * vhv[kb][1]);
        w.y = cvt_pk_bf16(p2 * vhv[kb][2], p3 * vhv[kb][3]);
        int chunk = (kb * 2 + (g >> 1)) ^ (lr & 7);
        *(uint2*)(Plds + wave * 2048 + lr * 128 + chunk * 16 + (g & 1) * 8) = w;
      }
      rsum += __shfl_xor(rsum, 16);
      rsum += __shfl_xor(rsum, 32);
      l_run += rsum;

      // --- PV ---
      s16x8 pa[2];
#pragma unroll
      for (int kk = 0; kk < 2; ++kk) {
        int chunk = (kk * 4 + g) ^ (lr & 7);
        pa[kk] = *(const s16x8*)(Plds + wave * 2048 + lr * 128 + chunk * 16);
      }
#pragma unroll
      for (int dc = 0; dc < 8; ++dc) {
#pragma unroll
        for (int kk = 0; kk < 2; ++kk) {
          int d = dc * 16 + lr;
          int chunk = (kk * 4 + g) ^ (d & 7);
          s16x8 vf = *(const s16x8*)(Vl + d * 128 + chunk * 16);
          oacc[dc] = __builtin_amdgcn_mfma_f32_16x16x32_bf16(pa[kk], vf, oacc[dc], 0, 0, 0);
        }
      }
      // end-of-tile barrier: all waves done reading buf[cur] before next overwrite
      __builtin_amdgcn_sched_barrier(0);
      __builtin_amdgcn_s_barrier();
    }
    // --- epilogue: fetch 1/l for q=4g+r via shfl, store O[b,n,h,d] ---
    float inv = 1.0f / l_run;
#pragma unroll
    for (int r = 0; r < 4; ++r) {
      float invr = __shfl(inv, 4 * g + r);
      int qout = qbase + 4 * g + r;
      unsigned short* orow = O + (((size_t)b * NN + qout) * HH + h) * DD;
#pragma unroll
      for (int dc = 0; dc < 8; ++dc) orow[dc * 16 + lr] = f2bf(oacc[dc][r] * invr);
    }
  }
}

// ---------------- launch -----------------------------------------------------
extern "C" void kernel_launch(void* const* d_in, const int* in_sizes, int n_in,
                              void* d_out, int out_size, void* d_ws, size_t ws_size,
                              hipStream_t stream) {
  const float* x = (const float*)d_in[0];
  const float* Wq = (const float*)d_in[1];
  const float* Wkv = (const float*)d_in[2];
  const float* Wkvh = (const float*)d_in[3];
  const float* Wo = (const float*)d_in[4];
  float* out = (float*)d_out;
  char* ws = (char*)d_ws;

  unsigned short* xb    = (unsigned short*)(ws + 0);          // 16 MB (b*n, E)
  unsigned short* obuf  = xb;                                  // alias: x dead by attn
  unsigned short* wqkv  = (unsigned short*)(ws + 16777216);    // 9.4 MB [Wq;Wkv] bf16
  unsigned short* vtb   = wqkv;                                // alias: wqkv dead after qkv GEMM
  unsigned short* wob   = (unsigned short*)(ws + 26214400);    // 8 MB
  unsigned short* qkv   = (unsigned short*)(ws + 34603008);    // 18 MB (b*n, 2304)
  unsigned short* wkvhb = (unsigned short*)(ws + 53477376);    // 128 KB Wkvh bf16
  float*          kvhb  = (float*)(ws + 53608448);             // 512 KB packed [b][h][n]{k,v}
  unsigned short* qrope = (unsigned short*)(ws + 54132736);    // 16 MB (b*h, n, d)
  unsigned short* krope = (unsigned short*)(ws + 70909952);    // 1 MB (b*n, d)

  f2b_kernel<<<8192, 256, 0, stream>>>(x, xb, 2097152);
  f2b_kernel<<<4096, 256, 0, stream>>>(Wq, wqkv, 1048576);
  f2b_kernel<<<512, 256, 0, stream>>>(Wkv, wqkv + 4194304, 131072);
  f2b_kernel<<<4096, 256, 0, stream>>>(Wo, wob, 1048576);
  f2b_kernel<<<64, 256, 0, stream>>>(Wkvh, wkvhb, 16384);

  gemm_bt<<<576, 256, 0, stream>>>(xb, wqkv, qkv, (float*)nullptr, 4096, NQKV, 2048);
  kvh_mfma<<<128, 256, 0, stream>>>(xb, wkvhb, kvhb);

  rope_q<<<16384, 256, 0, stream>>>(qkv, qrope);
  rope_k<<<1024, 256, 0, stream>>>(qkv, krope);
  vtrans<<<256, 256, 0, stream>>>(qkv, vtb);

  dim3 ag(16, HH, BB);
  attn<<<ag, 256, 0, stream>>>(qrope, krope, vtb, kvhb, obuf);

  gemm_bt<<<512, 256, 0, stream>>>(obuf, wob, (unsigned short*)nullptr, out, 4096, 2048, 2048);
}